// Round 1
// baseline (980.573 us; speedup 1.0000x reference)
//
#include <hip/hip_runtime.h>
#include <hip/hip_bf16.h>

typedef __attribute__((ext_vector_type(4))) float f32x4;
typedef __attribute__((ext_vector_type(8))) short bf16x8;
typedef __attribute__((ext_vector_type(8))) unsigned short u16x8;

#define NEG_BIG (-1e30f)

static __device__ __forceinline__ ushort f2b(float f) {
  union { float f; unsigned u; } v; v.f = f;
  unsigned r = v.u + 0x7fffu + ((v.u >> 16) & 1u);
  return (ushort)(r >> 16);
}

static __device__ __forceinline__ void gload_lds16(const void* g, void* l) {
  __builtin_amdgcn_global_load_lds(
      (__attribute__((address_space(1))) void*)(g),
      (__attribute__((address_space(3))) void*)(l), 16, 0, 0);
}

// ---------------- weight transpose + cast: Wt[n][k] = bf16(W[k][n]) -----------
__global__ __launch_bounds__(256) void transpose_cast_kernel(
    const float* __restrict__ W, ushort* __restrict__ Wt, int K, int N) {
  __shared__ float tile[32][33];
  const int n0 = blockIdx.x * 32, k0 = blockIdx.y * 32;
  const int tx = threadIdx.x, ty = threadIdx.y;  // 32 x 8
#pragma unroll
  for (int r = 0; r < 32; r += 8)
    tile[ty + r][tx] = W[(size_t)(k0 + ty + r) * N + n0 + tx];
  __syncthreads();
#pragma unroll
  for (int r = 0; r < 32; r += 8)
    Wt[(size_t)(n0 + ty + r) * K + k0 + tx] = f2b(tile[tx][ty + r]);
}

// ---------------- layernorm (rows of 1024 fp32) -> bf16 ----------------------
__global__ __launch_bounds__(256) void ln_kernel(
    const float* __restrict__ x, const float* __restrict__ g,
    const float* __restrict__ bb, ushort* __restrict__ out) {
  const int row = blockIdx.x;
  const float* xr = x + (size_t)row * 1024;
  const float4 v = *(const float4*)&xr[threadIdx.x * 4];
  float s = v.x + v.y + v.z + v.w;
  float s2 = v.x * v.x + v.y * v.y + v.z * v.z + v.w * v.w;
#pragma unroll
  for (int off = 32; off > 0; off >>= 1) {
    s += __shfl_down(s, off);
    s2 += __shfl_down(s2, off);
  }
  __shared__ float red[8];
  const int lane = threadIdx.x & 63, wv = threadIdx.x >> 6;
  if (lane == 0) { red[wv] = s; red[4 + wv] = s2; }
  __syncthreads();
  s = red[0] + red[1] + red[2] + red[3];
  s2 = red[4] + red[5] + red[6] + red[7];
  const float mu = s * (1.0f / 1024.0f);
  const float rs = rsqrtf(s2 * (1.0f / 1024.0f) - mu * mu + 1e-5f);
  const int c = threadIdx.x * 4;
  ushort4 o;
  o.x = f2b((v.x - mu) * rs * g[c + 0] + bb[c + 0]);
  o.y = f2b((v.y - mu) * rs * g[c + 1] + bb[c + 1]);
  o.z = f2b((v.z - mu) * rs * g[c + 2] + bb[c + 2]);
  o.w = f2b((v.w - mu) * rs * g[c + 3] + bb[c + 3]);
  *(ushort4*)&out[(size_t)row * 1024 + c] = o;
}

// ---------------- GEMM C = A(bf16[M,K]) * Bt(bf16[N,K])^T --------------------
// MODE 0: store bf16.  MODE 1: store fp32 = acc + bias[col] + res[row,col].
template <int MODE>
__global__ __launch_bounds__(256) void gemm_bt_kernel(
    const ushort* __restrict__ A, const ushort* __restrict__ Bt,
    const int M, const int N, const int K,
    ushort* __restrict__ Cb, float* __restrict__ Cf,
    const float* __restrict__ bias, const float* __restrict__ res) {
  __shared__ __align__(16) ushort lsA[128 * 32];
  __shared__ __align__(16) ushort lsB[128 * 32];
  const int ntn = N >> 7;
  const int bn = blockIdx.x % ntn;
  const int bm = blockIdx.x / ntn;
  const int tid = threadIdx.x;
  const int lane = tid & 63, wv = tid >> 6;
  const int wr = wv >> 1, wc = wv & 1;
  const int fr = lane & 15, fq = lane >> 4;

  f32x4 acc[4][4];
#pragma unroll
  for (int m = 0; m < 4; m++)
#pragma unroll
    for (int nn = 0; nn < 4; nn++) acc[m][nn] = (f32x4)0.0f;

  const ushort* Ab = A + (size_t)bm * 128 * K;
  const ushort* Bb = Bt + (size_t)bn * 128 * K;
  const int r0 = tid >> 2;
  const int cseg = (tid & 3) * 8;

  for (int k0 = 0; k0 < K; k0 += 32) {
    gload_lds16(Ab + (size_t)r0 * K + (k0 + cseg), &lsA[wv * 512]);
    gload_lds16(Ab + (size_t)(r0 + 64) * K + (k0 + cseg), &lsA[wv * 512 + 2048]);
    gload_lds16(Bb + (size_t)r0 * K + (k0 + cseg), &lsB[wv * 512]);
    gload_lds16(Bb + (size_t)(r0 + 64) * K + (k0 + cseg), &lsB[wv * 512 + 2048]);
    __syncthreads();
    bf16x8 af[4], bfv[4];
#pragma unroll
    for (int m = 0; m < 4; m++)
      af[m] = *(const bf16x8*)&lsA[(wr * 64 + m * 16 + fr) * 32 + fq * 8];
#pragma unroll
    for (int nn = 0; nn < 4; nn++)
      bfv[nn] = *(const bf16x8*)&lsB[(wc * 64 + nn * 16 + fr) * 32 + fq * 8];
#pragma unroll
    for (int m = 0; m < 4; m++)
#pragma unroll
      for (int nn = 0; nn < 4; nn++)
        acc[m][nn] = __builtin_amdgcn_mfma_f32_16x16x32_bf16(af[m], bfv[nn], acc[m][nn], 0, 0, 0);
    __syncthreads();
  }

  const int rowb = bm * 128 + wr * 64 + fq * 4;
  const int colb = bn * 128 + wc * 64 + fr;
#pragma unroll
  for (int m = 0; m < 4; m++) {
#pragma unroll
    for (int nn = 0; nn < 4; nn++) {
      const int col = colb + nn * 16;
#pragma unroll
      for (int j = 0; j < 4; j++) {
        const int row = rowb + m * 16 + j;
        const float vv = acc[m][nn][j];
        if (MODE == 0) {
          Cb[(size_t)row * N + col] = f2b(vv);
        } else {
          Cf[(size_t)row * N + col] = vv + bias[col] + res[(size_t)row * N + col];
        }
      }
    }
  }
}

// ---------------- GEGLU GEMM: u = (A*W1t[a]^T + b1a) * gelu(A*W1t[g]^T + b1g) -
__global__ __launch_bounds__(256) void gemm_geglu_kernel(
    const ushort* __restrict__ A, const ushort* __restrict__ W1t,
    const float* __restrict__ b1, ushort* __restrict__ U) {
  const int K = 1024;
  __shared__ __align__(16) ushort lsA[128 * 32];
  __shared__ __align__(16) ushort lsBa[128 * 32];
  __shared__ __align__(16) ushort lsBg[128 * 32];
  const int bn = blockIdx.x & 15;   // 2048/128 = 16 col tiles
  const int bm = blockIdx.x >> 4;
  const int tid = threadIdx.x;
  const int lane = tid & 63, wv = tid >> 6;
  const int wr = wv >> 1, wc = wv & 1;
  const int fr = lane & 15, fq = lane >> 4;

  f32x4 acca[4][4], accg[4][4];
#pragma unroll
  for (int m = 0; m < 4; m++)
#pragma unroll
    for (int nn = 0; nn < 4; nn++) { acca[m][nn] = (f32x4)0.0f; accg[m][nn] = (f32x4)0.0f; }

  const ushort* Ab = A + (size_t)bm * 128 * K;
  const ushort* Bab = W1t + (size_t)bn * 128 * K;
  const ushort* Bgb = W1t + (size_t)(2048 + bn * 128) * K;
  const int r0 = tid >> 2;
  const int cseg = (tid & 3) * 8;

  for (int k0 = 0; k0 < K; k0 += 32) {
    gload_lds16(Ab + (size_t)r0 * K + (k0 + cseg), &lsA[wv * 512]);
    gload_lds16(Ab + (size_t)(r0 + 64) * K + (k0 + cseg), &lsA[wv * 512 + 2048]);
    gload_lds16(Bab + (size_t)r0 * K + (k0 + cseg), &lsBa[wv * 512]);
    gload_lds16(Bab + (size_t)(r0 + 64) * K + (k0 + cseg), &lsBa[wv * 512 + 2048]);
    gload_lds16(Bgb + (size_t)r0 * K + (k0 + cseg), &lsBg[wv * 512]);
    gload_lds16(Bgb + (size_t)(r0 + 64) * K + (k0 + cseg), &lsBg[wv * 512 + 2048]);
    __syncthreads();
    bf16x8 af[4], ba[4], bg[4];
#pragma unroll
    for (int m = 0; m < 4; m++)
      af[m] = *(const bf16x8*)&lsA[(wr * 64 + m * 16 + fr) * 32 + fq * 8];
#pragma unroll
    for (int nn = 0; nn < 4; nn++) {
      ba[nn] = *(const bf16x8*)&lsBa[(wc * 64 + nn * 16 + fr) * 32 + fq * 8];
      bg[nn] = *(const bf16x8*)&lsBg[(wc * 64 + nn * 16 + fr) * 32 + fq * 8];
    }
#pragma unroll
    for (int m = 0; m < 4; m++)
#pragma unroll
      for (int nn = 0; nn < 4; nn++) {
        acca[m][nn] = __builtin_amdgcn_mfma_f32_16x16x32_bf16(af[m], ba[nn], acca[m][nn], 0, 0, 0);
        accg[m][nn] = __builtin_amdgcn_mfma_f32_16x16x32_bf16(af[m], bg[nn], accg[m][nn], 0, 0, 0);
      }
    __syncthreads();
  }

  const int rowb = bm * 128 + wr * 64 + fq * 4;
  const int colb = bn * 128 + wc * 64 + fr;
#pragma unroll
  for (int m = 0; m < 4; m++) {
#pragma unroll
    for (int nn = 0; nn < 4; nn++) {
      const int col = colb + nn * 16;
      const float b1a = b1[col];
      const float b1g = b1[2048 + col];
#pragma unroll
      for (int j = 0; j < 4; j++) {
        const int row = rowb + m * 16 + j;
        const float a = acca[m][nn][j] + b1a;
        const float gg = accg[m][nn][j] + b1g;
        const float gel = 0.5f * gg * (1.0f + erff(gg * 0.70710678118654752f));
        U[(size_t)row * 2048 + col] = f2b(a * gel);
      }
    }
  }
}

// ---------------- windowed causal attention ---------------------------------
// grid: (b*H + h)*NW + n ; 256 threads = 4 waves, wave wv owns q rows wv*64..+63
__global__ __launch_bounds__(256) void attn_kernel(
    const ushort* __restrict__ Q, const ushort* __restrict__ Kb,
    const ushort* __restrict__ Vb, ushort* __restrict__ O) {
  const int bx = blockIdx.x;
  const int n = bx & 15;
  const int h = (bx >> 4) & 15;
  const int b = bx >> 8;
  const int tid = threadIdx.x;
  const int lane = tid & 63, wv = tid >> 6;
  const int fr = lane & 15, fq = lane >> 4;

  __shared__ __align__(16) ushort Kl[64 * 72];
  __shared__ __align__(16) ushort Vt[64 * 72];
  __shared__ __align__(16) ushort Pl[4][64 * 72];

  const size_t qrow0 = (size_t)b * 4096 + (size_t)n * 256;

  bf16x8 qf[4][2];
#pragma unroll
  for (int m = 0; m < 4; m++)
#pragma unroll
    for (int kh = 0; kh < 2; kh++)
      qf[m][kh] = *(const bf16x8*)&Q[(qrow0 + wv * 64 + m * 16 + fr) * 1024 + h * 64 + kh * 32 + fq * 8];

  f32x4 oacc[4][4];
#pragma unroll
  for (int m = 0; m < 4; m++)
#pragma unroll
    for (int d = 0; d < 4; d++) oacc[m][d] = (f32x4)0.0f;

  float mrun[4][4], lrun[4][4];
#pragma unroll
  for (int m = 0; m < 4; m++)
#pragma unroll
    for (int j = 0; j < 4; j++) { mrun[m][j] = NEG_BIG; lrun[m][j] = 0.0f; }

  const int c0 = (n == 0) ? 4 : 0;
  for (int c = c0; c < 8; c++) {
    const size_t kvrow0 =
        (size_t)((long long)b * 4096 + (long long)n * 256 + (long long)c * 64 - 256);
#pragma unroll
    for (int p = 0; p < 2; p++) {
      const int s = tid + p * 256;
      const int rr = s >> 3, cs2 = s & 7;
      *(u16x8*)&Kl[rr * 72 + cs2 * 8] =
          *(const u16x8*)&Kb[(kvrow0 + rr) * 1024 + h * 64 + cs2 * 8];
      const u16x8 vvv = *(const u16x8*)&Vb[(kvrow0 + rr) * 1024 + h * 64 + cs2 * 8];
#pragma unroll
      for (int i = 0; i < 8; i++) Vt[(cs2 * 8 + i) * 72 + rr] = vvv[i];
    }
    __syncthreads();

    if (c <= wv + 4) {
      f32x4 sa[4][4];
#pragma unroll
      for (int m = 0; m < 4; m++)
#pragma unroll
        for (int nn = 0; nn < 4; nn++) sa[m][nn] = (f32x4)0.0f;
#pragma unroll
      for (int kh = 0; kh < 2; kh++) {
#pragma unroll
        for (int nn = 0; nn < 4; nn++) {
          const bf16x8 bk = *(const bf16x8*)&Kl[(nn * 16 + fr) * 72 + kh * 32 + fq * 8];
#pragma unroll
          for (int m = 0; m < 4; m++)
            sa[m][nn] = __builtin_amdgcn_mfma_f32_16x16x32_bf16(qf[m][kh], bk, sa[m][nn], 0, 0, 0);
        }
      }
      const bool diag = (c == wv + 4);
      float pmax[4][4], alpha[4][4], rsum[4][4];
#pragma unroll
      for (int m = 0; m < 4; m++)
#pragma unroll
        for (int j = 0; j < 4; j++) pmax[m][j] = NEG_BIG;
#pragma unroll
      for (int m = 0; m < 4; m++)
#pragma unroll
        for (int nn = 0; nn < 4; nn++)
#pragma unroll
          for (int j = 0; j < 4; j++) {
            float vv = sa[m][nn][j] * 0.125f;
            if (diag && (nn * 16 + fr > m * 16 + fq * 4 + j)) vv = NEG_BIG;
            sa[m][nn][j] = vv;
            pmax[m][j] = fmaxf(pmax[m][j], vv);
          }
#pragma unroll
      for (int m = 0; m < 4; m++)
#pragma unroll
        for (int j = 0; j < 4; j++) {
          float t = pmax[m][j];
          t = fmaxf(t, __shfl_xor(t, 1));
          t = fmaxf(t, __shfl_xor(t, 2));
          t = fmaxf(t, __shfl_xor(t, 4));
          t = fmaxf(t, __shfl_xor(t, 8));
          const float mn = fmaxf(mrun[m][j], t);
          const float al = __expf(mrun[m][j] - mn);
          mrun[m][j] = mn;
          lrun[m][j] *= al;
          alpha[m][j] = al;
          rsum[m][j] = 0.0f;
        }
#pragma unroll
      for (int m = 0; m < 4; m++)
#pragma unroll
        for (int nn = 0; nn < 4; nn++)
#pragma unroll
          for (int j = 0; j < 4; j++) {
            const float p = __expf(sa[m][nn][j] - mrun[m][j]);
            sa[m][nn][j] = p;
            rsum[m][j] += p;
          }
#pragma unroll
      for (int m = 0; m < 4; m++)
#pragma unroll
        for (int j = 0; j < 4; j++) {
          float t = rsum[m][j];
          t += __shfl_xor(t, 1);
          t += __shfl_xor(t, 2);
          t += __shfl_xor(t, 4);
          t += __shfl_xor(t, 8);
          lrun[m][j] += t;
        }
#pragma unroll
      for (int m = 0; m < 4; m++)
#pragma unroll
        for (int d = 0; d < 4; d++)
#pragma unroll
          for (int j = 0; j < 4; j++) oacc[m][d][j] *= alpha[m][j];
#pragma unroll
      for (int m = 0; m < 4; m++)
#pragma unroll
        for (int nn = 0; nn < 4; nn++)
#pragma unroll
          for (int j = 0; j < 4; j++)
            Pl[wv][(m * 16 + fq * 4 + j) * 72 + nn * 16 + fr] = f2b(sa[m][nn][j]);
#pragma unroll
      for (int kh = 0; kh < 2; kh++) {
        bf16x8 pa[4], vb[4];
#pragma unroll
        for (int m = 0; m < 4; m++)
          pa[m] = *(const bf16x8*)&Pl[wv][(m * 16 + fr) * 72 + kh * 32 + fq * 8];
#pragma unroll
        for (int d = 0; d < 4; d++)
          vb[d] = *(const bf16x8*)&Vt[(d * 16 + fr) * 72 + kh * 32 + fq * 8];
#pragma unroll
        for (int m = 0; m < 4; m++)
#pragma unroll
          for (int d = 0; d < 4; d++)
            oacc[m][d] = __builtin_amdgcn_mfma_f32_16x16x32_bf16(pa[m], vb[d], oacc[m][d], 0, 0, 0);
      }
    }
    __syncthreads();
  }

#pragma unroll
  for (int m = 0; m < 4; m++)
#pragma unroll
    for (int d = 0; d < 4; d++)
#pragma unroll
      for (int j = 0; j < 4; j++) {
        const float o = oacc[m][d][j] / lrun[m][j];
        O[(qrow0 + wv * 64 + m * 16 + fq * 4 + j) * 1024 + h * 64 + d * 16 + fr] = f2b(o);
      }
}

// ---------------- host launcher ----------------------------------------------
extern "C" void kernel_launch(void* const* d_in, const int* in_sizes, int n_in,
                              void* d_out, int out_size, void* d_ws, size_t ws_size,
                              hipStream_t stream) {
  (void)in_sizes; (void)n_in; (void)out_size; (void)ws_size;
  const float* x     = (const float*)d_in[0];
  const float* ln1_g = (const float*)d_in[1];
  const float* ln1_b = (const float*)d_in[2];
  const float* ln2_g = (const float*)d_in[3];
  const float* ln2_b = (const float*)d_in[4];
  const float* Wq    = (const float*)d_in[5];
  const float* Wk    = (const float*)d_in[6];
  const float* Wv    = (const float*)d_in[7];
  const float* Wo    = (const float*)d_in[8];
  const float* bo    = (const float*)d_in[9];
  const float* W1    = (const float*)d_in[10];
  const float* b1    = (const float*)d_in[11];
  const float* W2    = (const float*)d_in[12];
  const float* b2    = (const float*)d_in[13];

  char* ws = (char*)d_ws;
  const size_t MB = 1ull << 20;
  ushort* WQT = (ushort*)(ws + 0 * MB);
  ushort* WKT = (ushort*)(ws + 2 * MB);
  ushort* WVT = (ushort*)(ws + 4 * MB);
  ushort* WOT = (ushort*)(ws + 6 * MB);
  ushort* W1T = (ushort*)(ws + 8 * MB);    // [4096,1024]
  ushort* W2T = (ushort*)(ws + 16 * MB);   // [1024,2048]
  ushort* LN1 = (ushort*)(ws + 20 * MB);   // 32MB; reused as attn_out; then U
  ushort* ATT = LN1;
  ushort* U   = (ushort*)(ws + 20 * MB);   // 64MB (20..84)
  ushort* QB  = (ushort*)(ws + 84 * MB);   // 32MB; reused as LN2
  ushort* LN2 = QB;
  ushort* KB  = (ushort*)(ws + 116 * MB);  // 32MB
  ushort* VB  = (ushort*)(ws + 148 * MB);  // 32MB
  float*  X1  = (float*)(ws + 116 * MB);   // 64MB over dead K,V
  float*  OUT = (float*)d_out;

  const dim3 tb(32, 8);
  transpose_cast_kernel<<<dim3(32, 32), tb, 0, stream>>>(Wq, WQT, 1024, 1024);
  transpose_cast_kernel<<<dim3(32, 32), tb, 0, stream>>>(Wk, WKT, 1024, 1024);
  transpose_cast_kernel<<<dim3(32, 32), tb, 0, stream>>>(Wv, WVT, 1024, 1024);
  transpose_cast_kernel<<<dim3(32, 32), tb, 0, stream>>>(Wo, WOT, 1024, 1024);
  transpose_cast_kernel<<<dim3(128, 32), tb, 0, stream>>>(W1, W1T, 1024, 4096);
  transpose_cast_kernel<<<dim3(32, 64), tb, 0, stream>>>(W2, W2T, 2048, 1024);

  ln_kernel<<<16384, 256, 0, stream>>>(x, ln1_g, ln1_b, LN1);

  gemm_bt_kernel<0><<<1024, 256, 0, stream>>>(LN1, WQT, 16384, 1024, 1024, QB, nullptr, nullptr, nullptr);
  gemm_bt_kernel<0><<<1024, 256, 0, stream>>>(LN1, WKT, 16384, 1024, 1024, KB, nullptr, nullptr, nullptr);
  gemm_bt_kernel<0><<<1024, 256, 0, stream>>>(LN1, WVT, 16384, 1024, 1024, VB, nullptr, nullptr, nullptr);

  attn_kernel<<<1024, 256, 0, stream>>>(QB, KB, VB, ATT);

  gemm_bt_kernel<1><<<1024, 256, 0, stream>>>(ATT, WOT, 16384, 1024, 1024, nullptr, X1, bo, x);

  ln_kernel<<<16384, 256, 0, stream>>>(X1, ln2_g, ln2_b, LN2);

  gemm_geglu_kernel<<<2048, 256, 0, stream>>>(LN2, W1T, b1, U);

  gemm_bt_kernel<1><<<1024, 256, 0, stream>>>(U, W2T, 16384, 1024, 2048, nullptr, OUT, b2, X1);
}

// Round 2
// 779.251 us; speedup vs baseline: 1.2584x; 1.2584x over previous
//
#include <hip/hip_runtime.h>
#include <hip/hip_bf16.h>

typedef __attribute__((ext_vector_type(4))) float f32x4;
typedef __attribute__((ext_vector_type(8))) short bf16x8;
typedef __attribute__((ext_vector_type(8))) unsigned short u16x8;

#define NEG_BIG (-1e30f)

static __device__ __forceinline__ ushort f2b(float f) {
  union { float f; unsigned u; } v; v.f = f;
  unsigned r = v.u + 0x7fffu + ((v.u >> 16) & 1u);
  return (ushort)(r >> 16);
}

static __device__ __forceinline__ float gelu_fast(float g) {
  // tanh approximation; |err| vs exact erf-gelu < ~3e-4 for |g|<6
  const float c0 = 0.7978845608028654f, c1 = 0.044715f;
  const float u = c0 * (g + c1 * g * g * g);
  const float e = __expf(2.0f * u);
  const float t = 1.0f - 2.0f / (e + 1.0f);
  return 0.5f * g * (1.0f + t);
}

static __device__ __forceinline__ void gload_lds16(const void* g, void* l) {
  __builtin_amdgcn_global_load_lds(
      (__attribute__((address_space(1))) void*)(g),
      (__attribute__((address_space(3))) void*)(l), 16, 0, 0);
}

// ---------------- weight transpose + cast: Wt[n][k] = bf16(W[k][n]) -----------
__global__ __launch_bounds__(256) void transpose_cast_kernel(
    const float* __restrict__ W, ushort* __restrict__ Wt, int K, int N) {
  __shared__ float tile[32][33];
  const int n0 = blockIdx.x * 32, k0 = blockIdx.y * 32;
  const int tx = threadIdx.x, ty = threadIdx.y;  // 32 x 8
#pragma unroll
  for (int r = 0; r < 32; r += 8)
    tile[ty + r][tx] = W[(size_t)(k0 + ty + r) * N + n0 + tx];
  __syncthreads();
#pragma unroll
  for (int r = 0; r < 32; r += 8)
    Wt[(size_t)(n0 + ty + r) * K + k0 + tx] = f2b(tile[tx][ty + r]);
}

// ---------------- layernorm (rows of 1024 fp32) -> bf16 ----------------------
__global__ __launch_bounds__(256) void ln_kernel(
    const float* __restrict__ x, const float* __restrict__ g,
    const float* __restrict__ bb, ushort* __restrict__ out) {
  const int row = blockIdx.x;
  const float* xr = x + (size_t)row * 1024;
  const float4 v = *(const float4*)&xr[threadIdx.x * 4];
  float s = v.x + v.y + v.z + v.w;
  float s2 = v.x * v.x + v.y * v.y + v.z * v.z + v.w * v.w;
#pragma unroll
  for (int off = 32; off > 0; off >>= 1) {
    s += __shfl_down(s, off);
    s2 += __shfl_down(s2, off);
  }
  __shared__ float red[8];
  const int lane = threadIdx.x & 63, wv = threadIdx.x >> 6;
  if (lane == 0) { red[wv] = s; red[4 + wv] = s2; }
  __syncthreads();
  s = red[0] + red[1] + red[2] + red[3];
  s2 = red[4] + red[5] + red[6] + red[7];
  const float mu = s * (1.0f / 1024.0f);
  const float rs = rsqrtf(s2 * (1.0f / 1024.0f) - mu * mu + 1e-5f);
  const int c = threadIdx.x * 4;
  ushort4 o;
  o.x = f2b((v.x - mu) * rs * g[c + 0] + bb[c + 0]);
  o.y = f2b((v.y - mu) * rs * g[c + 1] + bb[c + 1]);
  o.z = f2b((v.z - mu) * rs * g[c + 2] + bb[c + 2]);
  o.w = f2b((v.w - mu) * rs * g[c + 3] + bb[c + 3]);
  *(ushort4*)&out[(size_t)row * 1024 + c] = o;
}

// ---------------- GEMM C = A(bf16[M,K]) * Bt(bf16[N,K])^T --------------------
// MODE 0: store bf16.  MODE 1: store fp32 = acc + bias[col] + res[row,col].
template <int MODE>
__global__ __launch_bounds__(256) void gemm_bt_kernel(
    const ushort* __restrict__ A, const ushort* __restrict__ Bt,
    const int M, const int N, const int K,
    ushort* __restrict__ Cb, float* __restrict__ Cf,
    const float* __restrict__ bias, const float* __restrict__ res) {
  __shared__ __align__(16) ushort lsA[128 * 32];
  __shared__ __align__(16) ushort lsB[128 * 32];
  const int ntn = N >> 7;
  const int bn = blockIdx.x % ntn;
  const int bm = blockIdx.x / ntn;
  const int tid = threadIdx.x;
  const int lane = tid & 63, wv = tid >> 6;
  const int wr = wv >> 1, wc = wv & 1;
  const int fr = lane & 15, fq = lane >> 4;

  f32x4 acc[4][4];
#pragma unroll
  for (int m = 0; m < 4; m++)
#pragma unroll
    for (int nn = 0; nn < 4; nn++) acc[m][nn] = (f32x4)0.0f;

  const ushort* Ab = A + (size_t)bm * 128 * K;
  const ushort* Bb = Bt + (size_t)bn * 128 * K;
  const int r0 = tid >> 2;
  const int cseg = (tid & 3) * 8;

  for (int k0 = 0; k0 < K; k0 += 32) {
    gload_lds16(Ab + (size_t)r0 * K + (k0 + cseg), &lsA[wv * 512]);
    gload_lds16(Ab + (size_t)(r0 + 64) * K + (k0 + cseg), &lsA[wv * 512 + 2048]);
    gload_lds16(Bb + (size_t)r0 * K + (k0 + cseg), &lsB[wv * 512]);
    gload_lds16(Bb + (size_t)(r0 + 64) * K + (k0 + cseg), &lsB[wv * 512 + 2048]);
    __syncthreads();
    bf16x8 af[4], bfv[4];
#pragma unroll
    for (int m = 0; m < 4; m++)
      af[m] = *(const bf16x8*)&lsA[(wr * 64 + m * 16 + fr) * 32 + fq * 8];
#pragma unroll
    for (int nn = 0; nn < 4; nn++)
      bfv[nn] = *(const bf16x8*)&lsB[(wc * 64 + nn * 16 + fr) * 32 + fq * 8];
#pragma unroll
    for (int m = 0; m < 4; m++)
#pragma unroll
      for (int nn = 0; nn < 4; nn++)
        acc[m][nn] = __builtin_amdgcn_mfma_f32_16x16x32_bf16(af[m], bfv[nn], acc[m][nn], 0, 0, 0);
    __syncthreads();
  }

  const int rowb = bm * 128 + wr * 64 + fq * 4;
  const int colb = bn * 128 + wc * 64 + fr;
#pragma unroll
  for (int m = 0; m < 4; m++) {
#pragma unroll
    for (int nn = 0; nn < 4; nn++) {
      const int col = colb + nn * 16;
#pragma unroll
      for (int j = 0; j < 4; j++) {
        const int row = rowb + m * 16 + j;
        const float vv = acc[m][nn][j];
        if (MODE == 0) {
          Cb[(size_t)row * N + col] = f2b(vv);
        } else {
          Cf[(size_t)row * N + col] = vv + bias[col] + res[(size_t)row * N + col];
        }
      }
    }
  }
}

// ---------------- GEGLU GEMM (N-split to keep acc at 64 AGPR) ----------------
// Block computes rows bm*128..+128, cols bn*64..+64 of BOTH a and g halves,
// writes U = a * gelu(g).
__global__ __launch_bounds__(256) void gemm_geglu_kernel(
    const ushort* __restrict__ A, const ushort* __restrict__ W1t,
    const float* __restrict__ b1, ushort* __restrict__ U) {
  const int K = 1024;
  __shared__ __align__(16) ushort lsA[128 * 32];
  __shared__ __align__(16) ushort lsBa[64 * 32];
  __shared__ __align__(16) ushort lsBg[64 * 32];
  const int bn = blockIdx.x & 31;   // 2048/64 = 32 col tiles
  const int bm = blockIdx.x >> 5;
  const int tid = threadIdx.x;
  const int lane = tid & 63, wv = tid >> 6;
  const int wr = wv >> 1, wc = wv & 1;
  const int fr = lane & 15, fq = lane >> 4;

  f32x4 acca[4][2], accg[4][2];
#pragma unroll
  for (int m = 0; m < 4; m++)
#pragma unroll
    for (int nn = 0; nn < 2; nn++) { acca[m][nn] = (f32x4)0.0f; accg[m][nn] = (f32x4)0.0f; }

  const ushort* Ab = A + (size_t)bm * 128 * K;
  const ushort* Bab = W1t + (size_t)bn * 64 * K;
  const ushort* Bgb = W1t + (size_t)(2048 + bn * 64) * K;
  const int r0 = tid >> 2;
  const int cseg = (tid & 3) * 8;

  for (int k0 = 0; k0 < K; k0 += 32) {
    gload_lds16(Ab + (size_t)r0 * K + (k0 + cseg), &lsA[wv * 512]);
    gload_lds16(Ab + (size_t)(r0 + 64) * K + (k0 + cseg), &lsA[wv * 512 + 2048]);
    gload_lds16(Bab + (size_t)r0 * K + (k0 + cseg), &lsBa[wv * 512]);
    gload_lds16(Bgb + (size_t)r0 * K + (k0 + cseg), &lsBg[wv * 512]);
    __syncthreads();
    bf16x8 af[4], ba[2], bg[2];
#pragma unroll
    for (int m = 0; m < 4; m++)
      af[m] = *(const bf16x8*)&lsA[(wr * 64 + m * 16 + fr) * 32 + fq * 8];
#pragma unroll
    for (int nn = 0; nn < 2; nn++) {
      ba[nn] = *(const bf16x8*)&lsBa[(wc * 32 + nn * 16 + fr) * 32 + fq * 8];
      bg[nn] = *(const bf16x8*)&lsBg[(wc * 32 + nn * 16 + fr) * 32 + fq * 8];
    }
#pragma unroll
    for (int m = 0; m < 4; m++)
#pragma unroll
      for (int nn = 0; nn < 2; nn++) {
        acca[m][nn] = __builtin_amdgcn_mfma_f32_16x16x32_bf16(af[m], ba[nn], acca[m][nn], 0, 0, 0);
        accg[m][nn] = __builtin_amdgcn_mfma_f32_16x16x32_bf16(af[m], bg[nn], accg[m][nn], 0, 0, 0);
      }
    __syncthreads();
  }

  const int rowb = bm * 128 + wr * 64 + fq * 4;
  const int colb = bn * 64 + wc * 32 + fr;
#pragma unroll
  for (int m = 0; m < 4; m++) {
#pragma unroll
    for (int nn = 0; nn < 2; nn++) {
      const int col = colb + nn * 16;
      const float b1a = b1[col];
      const float b1g = b1[2048 + col];
#pragma unroll
      for (int j = 0; j < 4; j++) {
        const int row = rowb + m * 16 + j;
        const float a = acca[m][nn][j] + b1a;
        const float gg = accg[m][nn][j] + b1g;
        U[(size_t)row * 2048 + col] = f2b(a * gelu_fast(gg));
      }
    }
  }
}

// ---------------- windowed causal attention ---------------------------------
// grid: (b*H + h)*NW + n ; 256 threads = 4 waves, wave wv owns q rows wv*64..+63
// Q/K/V live in a fused [rows][3072] buffer (stride qs), O has stride 1024.
__global__ __launch_bounds__(256) void attn_kernel(
    const ushort* __restrict__ Q, const ushort* __restrict__ Kb,
    const ushort* __restrict__ Vb, ushort* __restrict__ O, const int qs) {
  const int bx = blockIdx.x;
  const int n = bx & 15;
  const int h = (bx >> 4) & 15;
  const int b = bx >> 8;
  const int tid = threadIdx.x;
  const int lane = tid & 63, wv = tid >> 6;
  const int fr = lane & 15, fq = lane >> 4;

  __shared__ __align__(16) ushort Kl[64 * 72];
  __shared__ __align__(16) ushort Vt[64 * 72];
  __shared__ __align__(16) ushort Pl[4][64 * 72];

  const size_t qrow0 = (size_t)b * 4096 + (size_t)n * 256;

  bf16x8 qf[4][2];
#pragma unroll
  for (int m = 0; m < 4; m++)
#pragma unroll
    for (int kh = 0; kh < 2; kh++)
      qf[m][kh] = *(const bf16x8*)&Q[(qrow0 + wv * 64 + m * 16 + fr) * qs + h * 64 + kh * 32 + fq * 8];

  f32x4 oacc[4][4];
#pragma unroll
  for (int m = 0; m < 4; m++)
#pragma unroll
    for (int d = 0; d < 4; d++) oacc[m][d] = (f32x4)0.0f;

  float mrun[4][4], lrun[4][4];
#pragma unroll
  for (int m = 0; m < 4; m++)
#pragma unroll
    for (int j = 0; j < 4; j++) { mrun[m][j] = NEG_BIG; lrun[m][j] = 0.0f; }

  const int c0 = (n == 0) ? 4 : 0;
  for (int c = c0; c < 8; c++) {
    const size_t kvrow0 =
        (size_t)((long long)b * 4096 + (long long)n * 256 + (long long)c * 64 - 256);
#pragma unroll
    for (int p = 0; p < 2; p++) {
      const int s = tid + p * 256;
      const int rr = s >> 3, cs2 = s & 7;
      *(u16x8*)&Kl[rr * 72 + cs2 * 8] =
          *(const u16x8*)&Kb[(kvrow0 + rr) * qs + h * 64 + cs2 * 8];
      const u16x8 vvv = *(const u16x8*)&Vb[(kvrow0 + rr) * qs + h * 64 + cs2 * 8];
#pragma unroll
      for (int i = 0; i < 8; i++) Vt[(cs2 * 8 + i) * 72 + rr] = vvv[i];
    }
    __syncthreads();

    if (c <= wv + 4) {
      f32x4 sa[4][4];
#pragma unroll
      for (int m = 0; m < 4; m++)
#pragma unroll
        for (int nn = 0; nn < 4; nn++) sa[m][nn] = (f32x4)0.0f;
#pragma unroll
      for (int kh = 0; kh < 2; kh++) {
#pragma unroll
        for (int nn = 0; nn < 4; nn++) {
          const bf16x8 bk = *(const bf16x8*)&Kl[(nn * 16 + fr) * 72 + kh * 32 + fq * 8];
#pragma unroll
          for (int m = 0; m < 4; m++)
            sa[m][nn] = __builtin_amdgcn_mfma_f32_16x16x32_bf16(qf[m][kh], bk, sa[m][nn], 0, 0, 0);
        }
      }
      const bool diag = (c == wv + 4);
      float pmax[4][4], alpha[4][4], rsum[4][4];
#pragma unroll
      for (int m = 0; m < 4; m++)
#pragma unroll
        for (int j = 0; j < 4; j++) pmax[m][j] = NEG_BIG;
#pragma unroll
      for (int m = 0; m < 4; m++)
#pragma unroll
        for (int nn = 0; nn < 4; nn++)
#pragma unroll
          for (int j = 0; j < 4; j++) {
            float vv = sa[m][nn][j] * 0.125f;
            if (diag && (nn * 16 + fr > m * 16 + fq * 4 + j)) vv = NEG_BIG;
            sa[m][nn][j] = vv;
            pmax[m][j] = fmaxf(pmax[m][j], vv);
          }
#pragma unroll
      for (int m = 0; m < 4; m++)
#pragma unroll
        for (int j = 0; j < 4; j++) {
          float t = pmax[m][j];
          t = fmaxf(t, __shfl_xor(t, 1));
          t = fmaxf(t, __shfl_xor(t, 2));
          t = fmaxf(t, __shfl_xor(t, 4));
          t = fmaxf(t, __shfl_xor(t, 8));
          const float mn = fmaxf(mrun[m][j], t);
          const float al = __expf(mrun[m][j] - mn);
          mrun[m][j] = mn;
          lrun[m][j] *= al;
          alpha[m][j] = al;
          rsum[m][j] = 0.0f;
        }
#pragma unroll
      for (int m = 0; m < 4; m++)
#pragma unroll
        for (int nn = 0; nn < 4; nn++)
#pragma unroll
          for (int j = 0; j < 4; j++) {
            const float p = __expf(sa[m][nn][j] - mrun[m][j]);
            sa[m][nn][j] = p;
            rsum[m][j] += p;
          }
#pragma unroll
      for (int m = 0; m < 4; m++)
#pragma unroll
        for (int j = 0; j < 4; j++) {
          float t = rsum[m][j];
          t += __shfl_xor(t, 1);
          t += __shfl_xor(t, 2);
          t += __shfl_xor(t, 4);
          t += __shfl_xor(t, 8);
          lrun[m][j] += t;
        }
#pragma unroll
      for (int m = 0; m < 4; m++)
#pragma unroll
        for (int d = 0; d < 4; d++)
#pragma unroll
          for (int j = 0; j < 4; j++) oacc[m][d][j] *= alpha[m][j];
#pragma unroll
      for (int m = 0; m < 4; m++)
#pragma unroll
        for (int nn = 0; nn < 4; nn++)
#pragma unroll
          for (int j = 0; j < 4; j++)
            Pl[wv][(m * 16 + fq * 4 + j) * 72 + nn * 16 + fr] = f2b(sa[m][nn][j]);
#pragma unroll
      for (int kh = 0; kh < 2; kh++) {
        bf16x8 pa[4], vb[4];
#pragma unroll
        for (int m = 0; m < 4; m++)
          pa[m] = *(const bf16x8*)&Pl[wv][(m * 16 + fr) * 72 + kh * 32 + fq * 8];
#pragma unroll
        for (int d = 0; d < 4; d++)
          vb[d] = *(const bf16x8*)&Vt[(d * 16 + fr) * 72 + kh * 32 + fq * 8];
#pragma unroll
        for (int m = 0; m < 4; m++)
#pragma unroll
          for (int d = 0; d < 4; d++)
            oacc[m][d] = __builtin_amdgcn_mfma_f32_16x16x32_bf16(pa[m], vb[d], oacc[m][d], 0, 0, 0);
      }
    }
    __syncthreads();
  }

#pragma unroll
  for (int m = 0; m < 4; m++)
#pragma unroll
    for (int d = 0; d < 4; d++)
#pragma unroll
      for (int j = 0; j < 4; j++) {
        const float o = oacc[m][d][j] / lrun[m][j];
        O[(qrow0 + wv * 64 + m * 16 + fq * 4 + j) * 1024 + h * 64 + d * 16 + fr] = f2b(o);
      }
}

// ---------------- host launcher ----------------------------------------------
extern "C" void kernel_launch(void* const* d_in, const int* in_sizes, int n_in,
                              void* d_out, int out_size, void* d_ws, size_t ws_size,
                              hipStream_t stream) {
  (void)in_sizes; (void)n_in; (void)out_size; (void)ws_size;
  const float* x     = (const float*)d_in[0];
  const float* ln1_g = (const float*)d_in[1];
  const float* ln1_b = (const float*)d_in[2];
  const float* ln2_g = (const float*)d_in[3];
  const float* ln2_b = (const float*)d_in[4];
  const float* Wq    = (const float*)d_in[5];
  const float* Wk    = (const float*)d_in[6];
  const float* Wv    = (const float*)d_in[7];
  const float* Wo    = (const float*)d_in[8];
  const float* bo    = (const float*)d_in[9];
  const float* W1    = (const float*)d_in[10];
  const float* b1    = (const float*)d_in[11];
  const float* W2    = (const float*)d_in[12];
  const float* b2    = (const float*)d_in[13];

  char* ws = (char*)d_ws;
  const size_t MB = 1ull << 20;
  ushort* WQKVT = (ushort*)(ws + 0 * MB);   // [3072,1024] (Wq^T|Wk^T|Wv^T)
  ushort* WOT = (ushort*)(ws + 6 * MB);     // [1024,1024]
  ushort* W1T = (ushort*)(ws + 8 * MB);     // [4096,1024]
  ushort* W2T = (ushort*)(ws + 16 * MB);    // [1024,2048]
  ushort* LN1 = (ushort*)(ws + 20 * MB);    // 32MB
  ushort* ATT = LN1;                        // over dead LN1
  ushort* QKV = (ushort*)(ws + 52 * MB);    // [16384,3072] bf16 = 96MB (52..148)
  ushort* LN2 = (ushort*)(ws + 52 * MB);    // over dead QKV
  ushort* U   = (ushort*)(ws + 84 * MB);    // 64MB (84..148) over dead QKV
  float*  X1  = (float*)d_out;              // residual stream kept in d_out
  float*  OUT = (float*)d_out;

  const dim3 tb(32, 8);
  transpose_cast_kernel<<<dim3(32, 32), tb, 0, stream>>>(Wq, WQKVT, 1024, 1024);
  transpose_cast_kernel<<<dim3(32, 32), tb, 0, stream>>>(Wk, WQKVT + (size_t)1024 * 1024, 1024, 1024);
  transpose_cast_kernel<<<dim3(32, 32), tb, 0, stream>>>(Wv, WQKVT + (size_t)2048 * 1024, 1024, 1024);
  transpose_cast_kernel<<<dim3(32, 32), tb, 0, stream>>>(Wo, WOT, 1024, 1024);
  transpose_cast_kernel<<<dim3(128, 32), tb, 0, stream>>>(W1, W1T, 1024, 4096);
  transpose_cast_kernel<<<dim3(32, 64), tb, 0, stream>>>(W2, W2T, 2048, 1024);

  ln_kernel<<<16384, 256, 0, stream>>>(x, ln1_g, ln1_b, LN1);

  // fused QKV: [16384,3072] = LN1 * WQKVT^T
  gemm_bt_kernel<0><<<128 * 24, 256, 0, stream>>>(LN1, WQKVT, 16384, 3072, 1024,
                                                  QKV, nullptr, nullptr, nullptr);

  attn_kernel<<<1024, 256, 0, stream>>>(QKV, QKV + 1024, QKV + 2048, ATT, 3072);

  // x1 = x + ATT*Wo^T + bo   (fp32, into d_out)
  gemm_bt_kernel<1><<<128 * 8, 256, 0, stream>>>(ATT, WOT, 16384, 1024, 1024,
                                                 nullptr, X1, bo, x);

  ln_kernel<<<16384, 256, 0, stream>>>(X1, ln2_g, ln2_b, LN2);

  gemm_geglu_kernel<<<128 * 32, 256, 0, stream>>>(LN2, W1T, b1, U);

  // out = x1 + U*W2^T + b2  (in-place on d_out)
  gemm_bt_kernel<1><<<128 * 8, 256, 0, stream>>>(U, W2T, 16384, 1024, 2048,
                                                 nullptr, OUT, b2, X1);
}

// Round 3
// 655.885 us; speedup vs baseline: 1.4950x; 1.1881x over previous
//
#include <hip/hip_runtime.h>
#include <hip/hip_bf16.h>

typedef __attribute__((ext_vector_type(4))) float f32x4;
typedef __attribute__((ext_vector_type(8))) short bf16x8;
typedef __attribute__((ext_vector_type(8))) unsigned short u16x8;

static __device__ __forceinline__ ushort f2b(float f) {
  union { float f; unsigned u; } v; v.f = f;
  unsigned r = v.u + 0x7fffu + ((v.u >> 16) & 1u);
  return (ushort)(r >> 16);
}

static __device__ __forceinline__ float gelu_fast(float g) {
  const float c0 = 0.7978845608028654f, c1 = 0.044715f;
  const float u = c0 * (g + c1 * g * g * g);
  const float e = __expf(2.0f * u);
  const float t = 1.0f - 2.0f / (e + 1.0f);
  return 0.5f * g * (1.0f + t);
}

static __device__ __forceinline__ void gload_lds16(const void* g, void* l) {
  __builtin_amdgcn_global_load_lds(
      (__attribute__((address_space(1))) void*)(g),
      (__attribute__((address_space(3))) void*)(l), 16, 0, 0);
}

// ---------------- weight transpose + cast: Wt[n][k] = bf16(W[k][n]) -----------
__global__ __launch_bounds__(256) void transpose_cast_kernel(
    const float* __restrict__ W, ushort* __restrict__ Wt, int K, int N) {
  __shared__ float tile[32][33];
  const int n0 = blockIdx.x * 32, k0 = blockIdx.y * 32;
  const int tx = threadIdx.x, ty = threadIdx.y;  // 32 x 8
#pragma unroll
  for (int r = 0; r < 32; r += 8)
    tile[ty + r][tx] = W[(size_t)(k0 + ty + r) * N + n0 + tx];
  __syncthreads();
#pragma unroll
  for (int r = 0; r < 32; r += 8)
    Wt[(size_t)(n0 + ty + r) * K + k0 + tx] = f2b(tile[tx][ty + r]);
}

// ---------------- layernorm (rows of 1024 fp32) -> bf16 ----------------------
__global__ __launch_bounds__(256) void ln_kernel(
    const float* __restrict__ x, const float* __restrict__ g,
    const float* __restrict__ bb, ushort* __restrict__ out) {
  const int row = blockIdx.x;
  const float* xr = x + (size_t)row * 1024;
  const float4 v = *(const float4*)&xr[threadIdx.x * 4];
  float s = v.x + v.y + v.z + v.w;
  float s2 = v.x * v.x + v.y * v.y + v.z * v.z + v.w * v.w;
#pragma unroll
  for (int off = 32; off > 0; off >>= 1) {
    s += __shfl_down(s, off);
    s2 += __shfl_down(s2, off);
  }
  __shared__ float red[8];
  const int lane = threadIdx.x & 63, wv = threadIdx.x >> 6;
  if (lane == 0) { red[wv] = s; red[4 + wv] = s2; }
  __syncthreads();
  s = red[0] + red[1] + red[2] + red[3];
  s2 = red[4] + red[5] + red[6] + red[7];
  const float mu = s * (1.0f / 1024.0f);
  const float rs = rsqrtf(s2 * (1.0f / 1024.0f) - mu * mu + 1e-5f);
  const int c = threadIdx.x * 4;
  ushort4 o;
  o.x = f2b((v.x - mu) * rs * g[c + 0] + bb[c + 0]);
  o.y = f2b((v.y - mu) * rs * g[c + 1] + bb[c + 1]);
  o.z = f2b((v.z - mu) * rs * g[c + 2] + bb[c + 2]);
  o.w = f2b((v.w - mu) * rs * g[c + 3] + bb[c + 3]);
  *(ushort4*)&out[(size_t)row * 1024 + c] = o;
}

// ---------------- GEMM C = A(bf16[M,K]) * Bt(bf16[N,K])^T --------------------
// MODE 0: store bf16.  MODE 1: fp32 = acc + bias[col] + res.  MODE 2: bf16,
// cols<1024 scaled by 0.125 (pre-scaled Q for attention).
template <int MODE>
__global__ __launch_bounds__(256) void gemm_bt_kernel(
    const ushort* __restrict__ A, const ushort* __restrict__ Bt,
    const int M, const int N, const int K,
    ushort* __restrict__ Cb, float* __restrict__ Cf,
    const float* __restrict__ bias, const float* __restrict__ res) {
  __shared__ __align__(16) ushort lsA[128 * 32];
  __shared__ __align__(16) ushort lsB[128 * 32];
  const int ntn = N >> 7;
  const int bn = blockIdx.x % ntn;
  const int bm = blockIdx.x / ntn;
  const int tid = threadIdx.x;
  const int lane = tid & 63, wv = tid >> 6;
  const int wr = wv >> 1, wc = wv & 1;
  const int fr = lane & 15, fq = lane >> 4;

  f32x4 acc[4][4];
#pragma unroll
  for (int m = 0; m < 4; m++)
#pragma unroll
    for (int nn = 0; nn < 4; nn++) acc[m][nn] = (f32x4)0.0f;

  const ushort* Ab = A + (size_t)bm * 128 * K;
  const ushort* Bb = Bt + (size_t)bn * 128 * K;
  const int r0 = tid >> 2;
  const int cseg = (tid & 3) * 8;

  for (int k0 = 0; k0 < K; k0 += 32) {
    gload_lds16(Ab + (size_t)r0 * K + (k0 + cseg), &lsA[wv * 512]);
    gload_lds16(Ab + (size_t)(r0 + 64) * K + (k0 + cseg), &lsA[wv * 512 + 2048]);
    gload_lds16(Bb + (size_t)r0 * K + (k0 + cseg), &lsB[wv * 512]);
    gload_lds16(Bb + (size_t)(r0 + 64) * K + (k0 + cseg), &lsB[wv * 512 + 2048]);
    __syncthreads();
    bf16x8 af[4], bfv[4];
#pragma unroll
    for (int m = 0; m < 4; m++)
      af[m] = *(const bf16x8*)&lsA[(wr * 64 + m * 16 + fr) * 32 + fq * 8];
#pragma unroll
    for (int nn = 0; nn < 4; nn++)
      bfv[nn] = *(const bf16x8*)&lsB[(wc * 64 + nn * 16 + fr) * 32 + fq * 8];
#pragma unroll
    for (int m = 0; m < 4; m++)
#pragma unroll
      for (int nn = 0; nn < 4; nn++)
        acc[m][nn] = __builtin_amdgcn_mfma_f32_16x16x32_bf16(af[m], bfv[nn], acc[m][nn], 0, 0, 0);
    __syncthreads();
  }

  const int rowb = bm * 128 + wr * 64 + fq * 4;
  const int colb = bn * 128 + wc * 64 + fr;
#pragma unroll
  for (int m = 0; m < 4; m++) {
#pragma unroll
    for (int nn = 0; nn < 4; nn++) {
      const int col = colb + nn * 16;
#pragma unroll
      for (int j = 0; j < 4; j++) {
        const int row = rowb + m * 16 + j;
        float vv = acc[m][nn][j];
        if (MODE == 0) {
          Cb[(size_t)row * N + col] = f2b(vv);
        } else if (MODE == 2) {
          if (col < 1024) vv *= 0.125f;
          Cb[(size_t)row * N + col] = f2b(vv);
        } else {
          Cf[(size_t)row * N + col] = vv + bias[col] + res[(size_t)row * N + col];
        }
      }
    }
  }
}

// ---------------- GEGLU GEMM (N-split to keep acc at 64 AGPR) ----------------
__global__ __launch_bounds__(256) void gemm_geglu_kernel(
    const ushort* __restrict__ A, const ushort* __restrict__ W1t,
    const float* __restrict__ b1, ushort* __restrict__ U) {
  const int K = 1024;
  __shared__ __align__(16) ushort lsA[128 * 32];
  __shared__ __align__(16) ushort lsBa[64 * 32];
  __shared__ __align__(16) ushort lsBg[64 * 32];
  const int bn = blockIdx.x & 31;
  const int bm = blockIdx.x >> 5;
  const int tid = threadIdx.x;
  const int lane = tid & 63, wv = tid >> 6;
  const int wr = wv >> 1, wc = wv & 1;
  const int fr = lane & 15, fq = lane >> 4;

  f32x4 acca[4][2], accg[4][2];
#pragma unroll
  for (int m = 0; m < 4; m++)
#pragma unroll
    for (int nn = 0; nn < 2; nn++) { acca[m][nn] = (f32x4)0.0f; accg[m][nn] = (f32x4)0.0f; }

  const ushort* Ab = A + (size_t)bm * 128 * K;
  const ushort* Bab = W1t + (size_t)bn * 64 * K;
  const ushort* Bgb = W1t + (size_t)(2048 + bn * 64) * K;
  const int r0 = tid >> 2;
  const int cseg = (tid & 3) * 8;

  for (int k0 = 0; k0 < K; k0 += 32) {
    gload_lds16(Ab + (size_t)r0 * K + (k0 + cseg), &lsA[wv * 512]);
    gload_lds16(Ab + (size_t)(r0 + 64) * K + (k0 + cseg), &lsA[wv * 512 + 2048]);
    gload_lds16(Bab + (size_t)r0 * K + (k0 + cseg), &lsBa[wv * 512]);
    gload_lds16(Bgb + (size_t)r0 * K + (k0 + cseg), &lsBg[wv * 512]);
    __syncthreads();
    bf16x8 af[4], ba[2], bg[2];
#pragma unroll
    for (int m = 0; m < 4; m++)
      af[m] = *(const bf16x8*)&lsA[(wr * 64 + m * 16 + fr) * 32 + fq * 8];
#pragma unroll
    for (int nn = 0; nn < 2; nn++) {
      ba[nn] = *(const bf16x8*)&lsBa[(wc * 32 + nn * 16 + fr) * 32 + fq * 8];
      bg[nn] = *(const bf16x8*)&lsBg[(wc * 32 + nn * 16 + fr) * 32 + fq * 8];
    }
#pragma unroll
    for (int m = 0; m < 4; m++)
#pragma unroll
      for (int nn = 0; nn < 2; nn++) {
        acca[m][nn] = __builtin_amdgcn_mfma_f32_16x16x32_bf16(af[m], ba[nn], acca[m][nn], 0, 0, 0);
        accg[m][nn] = __builtin_amdgcn_mfma_f32_16x16x32_bf16(af[m], bg[nn], accg[m][nn], 0, 0, 0);
      }
    __syncthreads();
  }

  const int rowb = bm * 128 + wr * 64 + fq * 4;
  const int colb = bn * 64 + wc * 32 + fr;
#pragma unroll
  for (int m = 0; m < 4; m++) {
#pragma unroll
    for (int nn = 0; nn < 2; nn++) {
      const int col = colb + nn * 16;
      const float b1a = b1[col];
      const float b1g = b1[2048 + col];
#pragma unroll
      for (int j = 0; j < 4; j++) {
        const int row = rowb + m * 16 + j;
        const float a = acca[m][nn][j] + b1a;
        const float gg = accg[m][nn][j] + b1g;
        U[(size_t)row * 2048 + col] = f2b(a * gelu_fast(gg));
      }
    }
  }
}

// ---------------- windowed causal attention (no-max online softmax) ----------
// grid: (b*H + h)*NW + n ; 4 waves, wave wv owns q rows wv*64..+63.
// Q pre-scaled by 1/8 (done in QKV GEMM epilogue).  p = exp(q.k) directly;
// row-sums kept as per-lane partials, reduced once at the end.
__global__ __launch_bounds__(256, 3) void attn_kernel(
    const ushort* __restrict__ Q, const ushort* __restrict__ Kb,
    const ushort* __restrict__ Vb, ushort* __restrict__ O, const int qs) {
  const int bx = blockIdx.x;
  const int n = bx & 15;
  const int h = (bx >> 4) & 15;
  const int b = bx >> 8;
  const int tid = threadIdx.x;
  const int lane = tid & 63, wv = tid >> 6;
  const int fr = lane & 15, fq = lane >> 4;

  __shared__ __align__(16) ushort Kl[64 * 72];      // 9216 B, stride 72
  __shared__ __align__(16) ushort Vt[64 * 70];      // 8960 B, V^T, stride 70
  __shared__ __align__(16) ushort Pl[4][64 * 68];   // 34816 B, stride 68
  // total 52992 B -> 3 blocks/CU

  const size_t qrow0 = (size_t)b * 4096 + (size_t)n * 256;

  bf16x8 qf[4][2];
#pragma unroll
  for (int m = 0; m < 4; m++)
#pragma unroll
    for (int kh = 0; kh < 2; kh++)
      qf[m][kh] = *(const bf16x8*)&Q[(qrow0 + wv * 64 + m * 16 + fr) * qs + h * 64 + kh * 32 + fq * 8];

  f32x4 oacc[4][4];
#pragma unroll
  for (int m = 0; m < 4; m++)
#pragma unroll
    for (int d = 0; d < 4; d++) oacc[m][d] = (f32x4)0.0f;

  float lsum[4][4];
#pragma unroll
  for (int m = 0; m < 4; m++)
#pragma unroll
    for (int j = 0; j < 4; j++) lsum[m][j] = 0.0f;

  const int c0 = (n == 0) ? 4 : 0;
  for (int c = c0; c < 8; c++) {
    const size_t kvrow0 =
        (size_t)((long long)b * 4096 + (long long)n * 256 + (long long)c * 64 - 256);
#pragma unroll
    for (int p = 0; p < 2; p++) {
      const int s = tid + p * 256;
      const int rr = s >> 3, cs2 = s & 7;
      *(u16x8*)&Kl[rr * 72 + cs2 * 8] =
          *(const u16x8*)&Kb[(kvrow0 + rr) * qs + h * 64 + cs2 * 8];
      const u16x8 vvv = *(const u16x8*)&Vb[(kvrow0 + rr) * qs + h * 64 + cs2 * 8];
#pragma unroll
      for (int i = 0; i < 8; i++) Vt[(cs2 * 8 + i) * 70 + rr] = vvv[i];
    }
    __syncthreads();

    if (c <= wv + 4) {
      const bool diag = (c == wv + 4);
      // S slice by nn to bound register pressure
#pragma unroll
      for (int nn = 0; nn < 4; nn++) {
        f32x4 sa[4];
#pragma unroll
        for (int m = 0; m < 4; m++) sa[m] = (f32x4)0.0f;
#pragma unroll
        for (int kh = 0; kh < 2; kh++) {
          const bf16x8 bk = *(const bf16x8*)&Kl[(nn * 16 + fr) * 72 + kh * 32 + fq * 8];
#pragma unroll
          for (int m = 0; m < 4; m++)
            sa[m] = __builtin_amdgcn_mfma_f32_16x16x32_bf16(qf[m][kh], bk, sa[m], 0, 0, 0);
        }
#pragma unroll
        for (int m = 0; m < 4; m++)
#pragma unroll
          for (int j = 0; j < 4; j++) {
            float p = __expf(sa[m][j]);
            if (diag && (nn * 16 + fr > m * 16 + fq * 4 + j)) p = 0.0f;
            lsum[m][j] += p;
            Pl[wv][(m * 16 + fq * 4 + j) * 68 + nn * 16 + fr] = f2b(p);
          }
      }
      // PV
      __builtin_amdgcn_s_setprio(1);
#pragma unroll
      for (int kh = 0; kh < 2; kh++) {
        bf16x8 pa[4];
#pragma unroll
        for (int m = 0; m < 4; m++)
          pa[m] = *(const bf16x8*)&Pl[wv][(m * 16 + fr) * 68 + kh * 32 + fq * 8];
#pragma unroll
        for (int d = 0; d < 4; d++) {
          const bf16x8 vb = *(const bf16x8*)&Vt[(d * 16 + fr) * 70 + kh * 32 + fq * 8];
#pragma unroll
          for (int m = 0; m < 4; m++)
            oacc[m][d] = __builtin_amdgcn_mfma_f32_16x16x32_bf16(pa[m], vb, oacc[m][d], 0, 0, 0);
        }
      }
      __builtin_amdgcn_s_setprio(0);
    }
    __syncthreads();
  }

  // one-time row-sum reduction across the 16 fr-lanes
  float rl[4][4];
#pragma unroll
  for (int m = 0; m < 4; m++)
#pragma unroll
    for (int j = 0; j < 4; j++) {
      float t = lsum[m][j];
      t += __shfl_xor(t, 1);
      t += __shfl_xor(t, 2);
      t += __shfl_xor(t, 4);
      t += __shfl_xor(t, 8);
      rl[m][j] = 1.0f / t;
    }

#pragma unroll
  for (int m = 0; m < 4; m++)
#pragma unroll
    for (int d = 0; d < 4; d++)
#pragma unroll
      for (int j = 0; j < 4; j++) {
        const float o = oacc[m][d][j] * rl[m][j];
        O[(qrow0 + wv * 64 + m * 16 + fq * 4 + j) * 1024 + h * 64 + d * 16 + fr] = f2b(o);
      }
}

// ---------------- host launcher ----------------------------------------------
extern "C" void kernel_launch(void* const* d_in, const int* in_sizes, int n_in,
                              void* d_out, int out_size, void* d_ws, size_t ws_size,
                              hipStream_t stream) {
  (void)in_sizes; (void)n_in; (void)out_size; (void)ws_size;
  const float* x     = (const float*)d_in[0];
  const float* ln1_g = (const float*)d_in[1];
  const float* ln1_b = (const float*)d_in[2];
  const float* ln2_g = (const float*)d_in[3];
  const float* ln2_b = (const float*)d_in[4];
  const float* Wq    = (const float*)d_in[5];
  const float* Wk    = (const float*)d_in[6];
  const float* Wv    = (const float*)d_in[7];
  const float* Wo    = (const float*)d_in[8];
  const float* bo    = (const float*)d_in[9];
  const float* W1    = (const float*)d_in[10];
  const float* b1    = (const float*)d_in[11];
  const float* W2    = (const float*)d_in[12];
  const float* b2    = (const float*)d_in[13];

  char* ws = (char*)d_ws;
  const size_t MB = 1ull << 20;
  ushort* WQKVT = (ushort*)(ws + 0 * MB);   // [3072,1024]
  ushort* WOT = (ushort*)(ws + 6 * MB);     // [1024,1024]
  ushort* W1T = (ushort*)(ws + 8 * MB);     // [4096,1024]
  ushort* W2T = (ushort*)(ws + 16 * MB);    // [1024,2048]
  ushort* LN1 = (ushort*)(ws + 20 * MB);    // 32MB
  ushort* ATT = LN1;
  ushort* QKV = (ushort*)(ws + 52 * MB);    // [16384,3072] = 96MB
  ushort* LN2 = (ushort*)(ws + 52 * MB);
  ushort* U   = (ushort*)(ws + 84 * MB);    // 64MB
  float*  X1  = (float*)d_out;
  float*  OUT = (float*)d_out;

  const dim3 tb(32, 8);
  transpose_cast_kernel<<<dim3(32, 32), tb, 0, stream>>>(Wq, WQKVT, 1024, 1024);
  transpose_cast_kernel<<<dim3(32, 32), tb, 0, stream>>>(Wk, WQKVT + (size_t)1024 * 1024, 1024, 1024);
  transpose_cast_kernel<<<dim3(32, 32), tb, 0, stream>>>(Wv, WQKVT + (size_t)2048 * 1024, 1024, 1024);
  transpose_cast_kernel<<<dim3(32, 32), tb, 0, stream>>>(Wo, WOT, 1024, 1024);
  transpose_cast_kernel<<<dim3(128, 32), tb, 0, stream>>>(W1, W1T, 1024, 4096);
  transpose_cast_kernel<<<dim3(32, 64), tb, 0, stream>>>(W2, W2T, 2048, 1024);

  ln_kernel<<<16384, 256, 0, stream>>>(x, ln1_g, ln1_b, LN1);

  // fused QKV (Q pre-scaled by 1/8 in epilogue)
  gemm_bt_kernel<2><<<128 * 24, 256, 0, stream>>>(LN1, WQKVT, 16384, 3072, 1024,
                                                  QKV, nullptr, nullptr, nullptr);

  attn_kernel<<<1024, 256, 0, stream>>>(QKV, QKV + 1024, QKV + 2048, ATT, 3072);

  gemm_bt_kernel<1><<<128 * 8, 256, 0, stream>>>(ATT, WOT, 16384, 1024, 1024,
                                                 nullptr, X1, bo, x);

  ln_kernel<<<16384, 256, 0, stream>>>(X1, ln2_g, ln2_b, LN2);

  gemm_geglu_kernel<<<128 * 32, 256, 0, stream>>>(LN2, W1T, b1, U);

  gemm_bt_kernel<1><<<128 * 8, 256, 0, stream>>>(U, W2T, 16384, 1024, 2048,
                                                 nullptr, OUT, b2, X1);
}

// Round 6
// 584.037 us; speedup vs baseline: 1.6790x; 1.1230x over previous
//
#include <hip/hip_runtime.h>
#include <hip/hip_bf16.h>

typedef __attribute__((ext_vector_type(4))) float f32x4;
typedef __attribute__((ext_vector_type(8))) short bf16x8;
typedef __attribute__((ext_vector_type(8))) unsigned short u16x8;

static __device__ __forceinline__ ushort f2b(float f) {
  union { float f; unsigned u; } v; v.f = f;
  unsigned r = v.u + 0x7fffu + ((v.u >> 16) & 1u);
  return (ushort)(r >> 16);
}

static __device__ __forceinline__ float gelu_fast(float g) {
  const float c0 = 0.7978845608028654f, c1 = 0.044715f;
  const float u = c0 * (g + c1 * g * g * g);
  const float e = __expf(2.0f * u);
  const float t = 1.0f - 2.0f / (e + 1.0f);
  return 0.5f * g * (1.0f + t);
}

static __device__ __forceinline__ void gload_lds16(const void* g, void* l) {
  __builtin_amdgcn_global_load_lds(
      (__attribute__((address_space(1))) void*)(g),
      (__attribute__((address_space(3))) void*)(l), 16, 0, 0);
}

// ---------------- weight transpose + cast: Wt[n][k] = bf16(W[k][n]) -----------
__global__ __launch_bounds__(256) void transpose_cast_kernel(
    const float* __restrict__ W, ushort* __restrict__ Wt, int K, int N) {
  __shared__ float tile[32][33];
  const int n0 = blockIdx.x * 32, k0 = blockIdx.y * 32;
  const int tx = threadIdx.x, ty = threadIdx.y;  // 32 x 8
#pragma unroll
  for (int r = 0; r < 32; r += 8)
    tile[ty + r][tx] = W[(size_t)(k0 + ty + r) * N + n0 + tx];
  __syncthreads();
#pragma unroll
  for (int r = 0; r < 32; r += 8)
    Wt[(size_t)(n0 + ty + r) * K + k0 + tx] = f2b(tile[tx][ty + r]);
}

// ---------------- layernorm (rows of 1024 fp32) -> bf16 ----------------------
__global__ __launch_bounds__(256) void ln_kernel(
    const float* __restrict__ x, const float* __restrict__ g,
    const float* __restrict__ bb, ushort* __restrict__ out) {
  const int row = blockIdx.x;
  const float* xr = x + (size_t)row * 1024;
  const float4 v = *(const float4*)&xr[threadIdx.x * 4];
  float s = v.x + v.y + v.z + v.w;
  float s2 = v.x * v.x + v.y * v.y + v.z * v.z + v.w * v.w;
#pragma unroll
  for (int off = 32; off > 0; off >>= 1) {
    s += __shfl_down(s, off);
    s2 += __shfl_down(s2, off);
  }
  __shared__ float red[8];
  const int lane = threadIdx.x & 63, wv = threadIdx.x >> 6;
  if (lane == 0) { red[wv] = s; red[4 + wv] = s2; }
  __syncthreads();
  s = red[0] + red[1] + red[2] + red[3];
  s2 = red[4] + red[5] + red[6] + red[7];
  const float mu = s * (1.0f / 1024.0f);
  const float rs = rsqrtf(s2 * (1.0f / 1024.0f) - mu * mu + 1e-5f);
  const int c = threadIdx.x * 4;
  ushort4 o;
  o.x = f2b((v.x - mu) * rs * g[c + 0] + bb[c + 0]);
  o.y = f2b((v.y - mu) * rs * g[c + 1] + bb[c + 1]);
  o.z = f2b((v.z - mu) * rs * g[c + 2] + bb[c + 2]);
  o.w = f2b((v.w - mu) * rs * g[c + 3] + bb[c + 3]);
  *(ushort4*)&out[(size_t)row * 1024 + c] = o;
}

// ---------------- 256x256 deep-pipelined GEMM: C = A[M,K] * Bt[N,K]^T --------
// 512 threads = 8 waves (2 wm x 4 wn); per-wave 128x64 output.
// 3 LDS buffers (BK=32), counted vmcnt(8): tiles t+1,t+2 stay in flight
// across raw s_barriers (no vmcnt(0) drain in the main loop).
// LDS XOR-swizzle via pre-swizzled global source + swizzled ds_read
// (linear gload_lds dest, rule #21): 8-way -> ~4-way conflicts.
// MODE 0: bf16 store. MODE 2: bf16, cols<1024 scaled 0.125 (Q pre-scale).
// MODE 1: fp32 store = acc + bias[col] + res[row,col].
template <int MODE>
__global__ __launch_bounds__(512) void gemm256_kernel(
    const ushort* __restrict__ A, const ushort* __restrict__ Bt,
    const int M, const int N, const int K,
    ushort* __restrict__ Cb, float* __restrict__ Cf,
    const float* __restrict__ bias, const float* __restrict__ res) {
  __shared__ __align__(16) ushort lds[3 * 16384];  // 3 x (A 8192 + B 8192) = 96 KB

  const int ntn = N >> 8;
  const int bn = blockIdx.x % ntn;
  const int bm = blockIdx.x / ntn;
  const int tid = threadIdx.x;
  const int l = tid & 63, w = tid >> 6;
  const int wm = w >> 2, wn = w & 3;
  const int fr = l & 15, fq = l >> 4;

  const ushort* Ab = A + (size_t)bm * 256 * K;
  const ushort* Bb = Bt + (size_t)bn * 256 * K;

  // staging: lane l covers row (w*2+i)*16 + (l>>2); inverse-swizzled col
  const int srow = (l >> 2);
  const int scol = (((l & 3) ^ ((l >> 2) & 3)) * 8);  // pre-swizzled source col

  f32x4 acc[8][4];
#pragma unroll
  for (int m = 0; m < 8; m++)
#pragma unroll
    for (int n = 0; n < 4; n++) acc[m][n] = (f32x4)0.0f;

  const int NT = K >> 5;

#define STAGE256(t)                                                            \
  {                                                                            \
    const int b3 = (t) % 3;                                                    \
    const size_t kk = (size_t)(t) * 32;                                        \
    _Pragma("unroll") for (int i = 0; i < 2; i++) {                            \
      const int r = (w * 2 + i) * 16 + srow;                                   \
      gload_lds16(Ab + (size_t)r * K + kk + scol,                              \
                  &lds[b3 * 16384 + (w * 2 + i) * 512]);                       \
      gload_lds16(Bb + (size_t)r * K + kk + scol,                              \
                  &lds[b3 * 16384 + 8192 + (w * 2 + i) * 512]);                \
    }                                                                          \
  }

  STAGE256(0);
  STAGE256(1);

  for (int t = 0; t < NT; ++t) {
    if (t + 2 < NT) {
      STAGE256(t + 2);
      asm volatile("s_waitcnt vmcnt(8)" ::: "memory");
    } else if (t + 1 < NT) {
      asm volatile("s_waitcnt vmcnt(4)" ::: "memory");
    } else {
      asm volatile("s_waitcnt vmcnt(0)" ::: "memory");
    }
    __builtin_amdgcn_s_barrier();
    asm volatile("" ::: "memory");

    const ushort* La = &lds[(t % 3) * 16384];
    const ushort* Lb = La + 8192;

    bf16x8 af[8], bf[4];
#pragma unroll
    for (int m = 0; m < 8; m++) {
      const int r = wm * 128 + m * 16 + fr;
      af[m] = *(const bf16x8*)&La[r * 32 + ((fq ^ (r & 3)) * 8)];
    }
#pragma unroll
    for (int n = 0; n < 4; n++) {
      const int r = wn * 64 + n * 16 + fr;
      bf[n] = *(const bf16x8*)&Lb[r * 32 + ((fq ^ (r & 3)) * 8)];
    }

    __builtin_amdgcn_s_setprio(1);
#pragma unroll
    for (int m = 0; m < 8; m++)
#pragma unroll
      for (int n = 0; n < 4; n++)
        acc[m][n] = __builtin_amdgcn_mfma_f32_16x16x32_bf16(af[m], bf[n], acc[m][n], 0, 0, 0);
    __builtin_amdgcn_s_setprio(0);

    asm volatile("" ::: "memory");
    __builtin_amdgcn_s_barrier();
  }
#undef STAGE256

  const int rowb = bm * 256 + wm * 128 + fq * 4;
  const int colb = bn * 256 + wn * 64 + fr;
#pragma unroll
  for (int m = 0; m < 8; m++) {
#pragma unroll
    for (int n = 0; n < 4; n++) {
      const int col = colb + n * 16;
#pragma unroll
      for (int j = 0; j < 4; j++) {
        const int row = rowb + m * 16 + j;
        float vv = acc[m][n][j];
        if (MODE == 0) {
          Cb[(size_t)row * N + col] = f2b(vv);
        } else if (MODE == 2) {
          if (col < 1024) vv *= 0.125f;
          Cb[(size_t)row * N + col] = f2b(vv);
        } else {
          Cf[(size_t)row * N + col] = vv + bias[col] + res[(size_t)row * N + col];
        }
      }
    }
  }
}

// ---------------- GEGLU GEMM (N-split to keep acc at 64 AGPR) ----------------
__global__ __launch_bounds__(256) void gemm_geglu_kernel(
    const ushort* __restrict__ A, const ushort* __restrict__ W1t,
    const float* __restrict__ b1, ushort* __restrict__ U) {
  const int K = 1024;
  __shared__ __align__(16) ushort lsA[128 * 32];
  __shared__ __align__(16) ushort lsBa[64 * 32];
  __shared__ __align__(16) ushort lsBg[64 * 32];
  const int bn = blockIdx.x & 31;
  const int bm = blockIdx.x >> 5;
  const int tid = threadIdx.x;
  const int lane = tid & 63, wv = tid >> 6;
  const int wr = wv >> 1, wc = wv & 1;
  const int fr = lane & 15, fq = lane >> 4;

  f32x4 acca[4][2], accg[4][2];
#pragma unroll
  for (int m = 0; m < 4; m++)
#pragma unroll
    for (int nn = 0; nn < 2; nn++) { acca[m][nn] = (f32x4)0.0f; accg[m][nn] = (f32x4)0.0f; }

  const ushort* Ab = A + (size_t)bm * 128 * K;
  const ushort* Bab = W1t + (size_t)bn * 64 * K;
  const ushort* Bgb = W1t + (size_t)(2048 + bn * 64) * K;
  const int r0 = tid >> 2;
  const int cseg = (tid & 3) * 8;

  for (int k0 = 0; k0 < K; k0 += 32) {
    gload_lds16(Ab + (size_t)r0 * K + (k0 + cseg), &lsA[wv * 512]);
    gload_lds16(Ab + (size_t)(r0 + 64) * K + (k0 + cseg), &lsA[wv * 512 + 2048]);
    gload_lds16(Bab + (size_t)r0 * K + (k0 + cseg), &lsBa[wv * 512]);
    gload_lds16(Bgb + (size_t)r0 * K + (k0 + cseg), &lsBg[wv * 512]);
    __syncthreads();
    bf16x8 af[4], ba[2], bg[2];
#pragma unroll
    for (int m = 0; m < 4; m++)
      af[m] = *(const bf16x8*)&lsA[(wr * 64 + m * 16 + fr) * 32 + fq * 8];
#pragma unroll
    for (int nn = 0; nn < 2; nn++) {
      ba[nn] = *(const bf16x8*)&lsBa[(wc * 32 + nn * 16 + fr) * 32 + fq * 8];
      bg[nn] = *(const bf16x8*)&lsBg[(wc * 32 + nn * 16 + fr) * 32 + fq * 8];
    }
#pragma unroll
    for (int m = 0; m < 4; m++)
#pragma unroll
      for (int nn = 0; nn < 2; nn++) {
        acca[m][nn] = __builtin_amdgcn_mfma_f32_16x16x32_bf16(af[m], ba[nn], acca[m][nn], 0, 0, 0);
        accg[m][nn] = __builtin_amdgcn_mfma_f32_16x16x32_bf16(af[m], bg[nn], accg[m][nn], 0, 0, 0);
      }
    __syncthreads();
  }

  const int rowb = bm * 128 + wr * 64 + fq * 4;
  const int colb = bn * 64 + wc * 32 + fr;
#pragma unroll
  for (int m = 0; m < 4; m++) {
#pragma unroll
    for (int nn = 0; nn < 2; nn++) {
      const int col = colb + nn * 16;
      const float b1a = b1[col];
      const float b1g = b1[2048 + col];
#pragma unroll
      for (int j = 0; j < 4; j++) {
        const int row = rowb + m * 16 + j;
        const float a = acca[m][nn][j] + b1a;
        const float gg = accg[m][nn][j] + b1g;
        U[(size_t)row * 2048 + col] = f2b(a * gelu_fast(gg));
      }
    }
  }
}

// ---------------- windowed causal attention (no-max online softmax) ----------
__global__ __launch_bounds__(256, 3) void attn_kernel(
    const ushort* __restrict__ Q, const ushort* __restrict__ Kb,
    const ushort* __restrict__ Vb, ushort* __restrict__ O, const int qs) {
  const int bx = blockIdx.x;
  const int n = bx & 15;
  const int h = (bx >> 4) & 15;
  const int b = bx >> 8;
  const int tid = threadIdx.x;
  const int lane = tid & 63, wv = tid >> 6;
  const int fr = lane & 15, fq = lane >> 4;

  __shared__ __align__(16) ushort Kl[64 * 72];
  __shared__ __align__(16) ushort Vt[64 * 70];
  __shared__ __align__(16) ushort Pl[4][64 * 68];

  const size_t qrow0 = (size_t)b * 4096 + (size_t)n * 256;

  bf16x8 qf[4][2];
#pragma unroll
  for (int m = 0; m < 4; m++)
#pragma unroll
    for (int kh = 0; kh < 2; kh++)
      qf[m][kh] = *(const bf16x8*)&Q[(qrow0 + wv * 64 + m * 16 + fr) * qs + h * 64 + kh * 32 + fq * 8];

  f32x4 oacc[4][4];
#pragma unroll
  for (int m = 0; m < 4; m++)
#pragma unroll
    for (int d = 0; d < 4; d++) oacc[m][d] = (f32x4)0.0f;

  float lsum[4][4];
#pragma unroll
  for (int m = 0; m < 4; m++)
#pragma unroll
    for (int j = 0; j < 4; j++) lsum[m][j] = 0.0f;

  const int c0 = (n == 0) ? 4 : 0;
  for (int c = c0; c < 8; c++) {
    const size_t kvrow0 =
        (size_t)((long long)b * 4096 + (long long)n * 256 + (long long)c * 64 - 256);
#pragma unroll
    for (int p = 0; p < 2; p++) {
      const int s = tid + p * 256;
      const int rr = s >> 3, cs2 = s & 7;
      *(u16x8*)&Kl[rr * 72 + cs2 * 8] =
          *(const u16x8*)&Kb[(kvrow0 + rr) * qs + h * 64 + cs2 * 8];
      const u16x8 vvv = *(const u16x8*)&Vb[(kvrow0 + rr) * qs + h * 64 + cs2 * 8];
#pragma unroll
      for (int i = 0; i < 8; i++) Vt[(cs2 * 8 + i) * 70 + rr] = vvv[i];
    }
    __syncthreads();

    if (c <= wv + 4) {
      const bool diag = (c == wv + 4);
#pragma unroll
      for (int nn = 0; nn < 4; nn++) {
        f32x4 sa[4];
#pragma unroll
        for (int m = 0; m < 4; m++) sa[m] = (f32x4)0.0f;
#pragma unroll
        for (int kh = 0; kh < 2; kh++) {
          const bf16x8 bk = *(const bf16x8*)&Kl[(nn * 16 + fr) * 72 + kh * 32 + fq * 8];
#pragma unroll
          for (int m = 0; m < 4; m++)
            sa[m] = __builtin_amdgcn_mfma_f32_16x16x32_bf16(qf[m][kh], bk, sa[m], 0, 0, 0);
        }
#pragma unroll
        for (int m = 0; m < 4; m++)
#pragma unroll
          for (int j = 0; j < 4; j++) {
            float p = __expf(sa[m][j]);
            if (diag && (nn * 16 + fr > m * 16 + fq * 4 + j)) p = 0.0f;
            lsum[m][j] += p;
            Pl[wv][(m * 16 + fq * 4 + j) * 68 + nn * 16 + fr] = f2b(p);
          }
      }
      __builtin_amdgcn_s_setprio(1);
#pragma unroll
      for (int kh = 0; kh < 2; kh++) {
        bf16x8 pa[4];
#pragma unroll
        for (int m = 0; m < 4; m++)
          pa[m] = *(const bf16x8*)&Pl[wv][(m * 16 + fr) * 68 + kh * 32 + fq * 8];
#pragma unroll
        for (int d = 0; d < 4; d++) {
          const bf16x8 vb = *(const bf16x8*)&Vt[(d * 16 + fr) * 70 + kh * 32 + fq * 8];
#pragma unroll
          for (int m = 0; m < 4; m++)
            oacc[m][d] = __builtin_amdgcn_mfma_f32_16x16x32_bf16(pa[m], vb, oacc[m][d], 0, 0, 0);
        }
      }
      __builtin_amdgcn_s_setprio(0);
    }
    __syncthreads();
  }

  float rl[4][4];
#pragma unroll
  for (int m = 0; m < 4; m++)
#pragma unroll
    for (int j = 0; j < 4; j++) {
      float t = lsum[m][j];
      t += __shfl_xor(t, 1);
      t += __shfl_xor(t, 2);
      t += __shfl_xor(t, 4);
      t += __shfl_xor(t, 8);
      rl[m][j] = 1.0f / t;
    }

#pragma unroll
  for (int m = 0; m < 4; m++)
#pragma unroll
    for (int d = 0; d < 4; d++)
#pragma unroll
      for (int j = 0; j < 4; j++) {
        const float o = oacc[m][d][j] * rl[m][j];
        O[(qrow0 + wv * 64 + m * 16 + fq * 4 + j) * 1024 + h * 64 + d * 16 + fr] = f2b(o);
      }
}

// ---------------- host launcher ----------------------------------------------
extern "C" void kernel_launch(void* const* d_in, const int* in_sizes, int n_in,
                              void* d_out, int out_size, void* d_ws, size_t ws_size,
                              hipStream_t stream) {
  (void)in_sizes; (void)n_in; (void)out_size; (void)ws_size;
  const float* x     = (const float*)d_in[0];
  const float* ln1_g = (const float*)d_in[1];
  const float* ln1_b = (const float*)d_in[2];
  const float* ln2_g = (const float*)d_in[3];
  const float* ln2_b = (const float*)d_in[4];
  const float* Wq    = (const float*)d_in[5];
  const float* Wk    = (const float*)d_in[6];
  const float* Wv    = (const float*)d_in[7];
  const float* Wo    = (const float*)d_in[8];
  const float* bo    = (const float*)d_in[9];
  const float* W1    = (const float*)d_in[10];
  const float* b1    = (const float*)d_in[11];
  const float* W2    = (const float*)d_in[12];
  const float* b2    = (const float*)d_in[13];

  char* ws = (char*)d_ws;
  const size_t MB = 1ull << 20;
  ushort* WQKVT = (ushort*)(ws + 0 * MB);   // [3072,1024]
  ushort* WOT = (ushort*)(ws + 6 * MB);     // [1024,1024]
  ushort* W1T = (ushort*)(ws + 8 * MB);     // [4096,1024]
  ushort* W2T = (ushort*)(ws + 16 * MB);    // [1024,2048]
  ushort* LN1 = (ushort*)(ws + 20 * MB);    // 32MB
  ushort* ATT = LN1;
  ushort* QKV = (ushort*)(ws + 52 * MB);    // [16384,3072] = 96MB
  ushort* LN2 = (ushort*)(ws + 52 * MB);
  ushort* U   = (ushort*)(ws + 84 * MB);    // 64MB
  float*  X1  = (float*)d_out;
  float*  OUT = (float*)d_out;

  const dim3 tb(32, 8);
  transpose_cast_kernel<<<dim3(32, 32), tb, 0, stream>>>(Wq, WQKVT, 1024, 1024);
  transpose_cast_kernel<<<dim3(32, 32), tb, 0, stream>>>(Wk, WQKVT + (size_t)1024 * 1024, 1024, 1024);
  transpose_cast_kernel<<<dim3(32, 32), tb, 0, stream>>>(Wv, WQKVT + (size_t)2048 * 1024, 1024, 1024);
  transpose_cast_kernel<<<dim3(32, 32), tb, 0, stream>>>(Wo, WOT, 1024, 1024);
  transpose_cast_kernel<<<dim3(128, 32), tb, 0, stream>>>(W1, W1T, 1024, 4096);
  transpose_cast_kernel<<<dim3(32, 64), tb, 0, stream>>>(W2, W2T, 2048, 1024);

  ln_kernel<<<16384, 256, 0, stream>>>(x, ln1_g, ln1_b, LN1);

  // fused QKV (Q pre-scaled by 1/8 in epilogue): [16384,3072]
  gemm256_kernel<2><<<64 * 12, 512, 0, stream>>>(LN1, WQKVT, 16384, 3072, 1024,
                                                 QKV, nullptr, nullptr, nullptr);

  attn_kernel<<<1024, 256, 0, stream>>>(QKV, QKV + 1024, QKV + 2048, ATT, 3072);

  // x1 = x + ATT*Wo^T + bo  (fp32, into d_out)
  gemm256_kernel<1><<<64 * 4, 512, 0, stream>>>(ATT, WOT, 16384, 1024, 1024,
                                                nullptr, X1, bo, x);

  ln_kernel<<<16384, 256, 0, stream>>>(X1, ln2_g, ln2_b, LN2);

  gemm_geglu_kernel<<<128 * 32, 256, 0, stream>>>(LN2, W1T, b1, U);

  // out = x1 + U*W2^T + b2  (in-place on d_out)
  gemm256_kernel<1><<<64 * 4, 512, 0, stream>>>(U, W2T, 16384, 1024, 2048,
                                                nullptr, OUT, b2, X1);
}

// Round 7
// 573.751 us; speedup vs baseline: 1.7091x; 1.0179x over previous
//
#include <hip/hip_runtime.h>
#include <hip/hip_bf16.h>

typedef __attribute__((ext_vector_type(4))) float f32x4;
typedef __attribute__((ext_vector_type(8))) short bf16x8;
typedef __attribute__((ext_vector_type(8))) unsigned short u16x8;

static __device__ __forceinline__ ushort f2b(float f) {
  union { float f; unsigned u; } v; v.f = f;
  unsigned r = v.u + 0x7fffu + ((v.u >> 16) & 1u);
  return (ushort)(r >> 16);
}

static __device__ __forceinline__ float gelu_fast(float g) {
  const float c0 = 0.7978845608028654f, c1 = 0.044715f;
  const float u = c0 * (g + c1 * g * g * g);
  const float e = __expf(2.0f * u);
  const float t = 1.0f - 2.0f / (e + 1.0f);
  return 0.5f * g * (1.0f + t);
}

static __device__ __forceinline__ void gload_lds16(const void* g, void* l) {
  __builtin_amdgcn_global_load_lds(
      (__attribute__((address_space(1))) void*)(g),
      (__attribute__((address_space(3))) void*)(l), 16, 0, 0);
}

// ---------------- weight transpose + cast: Wt[n][k] = bf16(W[k][n]) -----------
__global__ __launch_bounds__(256) void transpose_cast_kernel(
    const float* __restrict__ W, ushort* __restrict__ Wt, int K, int N) {
  __shared__ float tile[32][33];
  const int n0 = blockIdx.x * 32, k0 = blockIdx.y * 32;
  const int tx = threadIdx.x, ty = threadIdx.y;  // 32 x 8
#pragma unroll
  for (int r = 0; r < 32; r += 8)
    tile[ty + r][tx] = W[(size_t)(k0 + ty + r) * N + n0 + tx];
  __syncthreads();
#pragma unroll
  for (int r = 0; r < 32; r += 8)
    Wt[(size_t)(n0 + ty + r) * K + k0 + tx] = f2b(tile[tx][ty + r]);
}

// ---------------- layernorm (rows of 1024 fp32) -> bf16 ----------------------
__global__ __launch_bounds__(256) void ln_kernel(
    const float* __restrict__ x, const float* __restrict__ g,
    const float* __restrict__ bb, ushort* __restrict__ out) {
  const int row = blockIdx.x;
  const float* xr = x + (size_t)row * 1024;
  const float4 v = *(const float4*)&xr[threadIdx.x * 4];
  float s = v.x + v.y + v.z + v.w;
  float s2 = v.x * v.x + v.y * v.y + v.z * v.z + v.w * v.w;
#pragma unroll
  for (int off = 32; off > 0; off >>= 1) {
    s += __shfl_down(s, off);
    s2 += __shfl_down(s2, off);
  }
  __shared__ float red[8];
  const int lane = threadIdx.x & 63, wv = threadIdx.x >> 6;
  if (lane == 0) { red[wv] = s; red[4 + wv] = s2; }
  __syncthreads();
  s = red[0] + red[1] + red[2] + red[3];
  s2 = red[4] + red[5] + red[6] + red[7];
  const float mu = s * (1.0f / 1024.0f);
  const float rs = rsqrtf(s2 * (1.0f / 1024.0f) - mu * mu + 1e-5f);
  const int c = threadIdx.x * 4;
  ushort4 o;
  o.x = f2b((v.x - mu) * rs * g[c + 0] + bb[c + 0]);
  o.y = f2b((v.y - mu) * rs * g[c + 1] + bb[c + 1]);
  o.z = f2b((v.z - mu) * rs * g[c + 2] + bb[c + 2]);
  o.w = f2b((v.w - mu) * rs * g[c + 3] + bb[c + 3]);
  *(ushort4*)&out[(size_t)row * 1024 + c] = o;
}

// ---------------- 256x256 deep-pipelined GEMM: C = A[M,K] * Bt[N,K]^T --------
// 512 threads = 8 waves (2 wm x 4 wn); per-wave 128x64 output.
// 3 LDS buffers (BK=32), counted vmcnt(8); both-sides XOR swizzle.
template <int MODE>
__global__ __launch_bounds__(512) void gemm256_kernel(
    const ushort* __restrict__ A, const ushort* __restrict__ Bt,
    const int M, const int N, const int K,
    ushort* __restrict__ Cb, float* __restrict__ Cf,
    const float* __restrict__ bias, const float* __restrict__ res) {
  __shared__ __align__(16) ushort lds[3 * 16384];  // 96 KB

  const int ntn = N >> 8;
  const int bn = blockIdx.x % ntn;
  const int bm = blockIdx.x / ntn;
  const int tid = threadIdx.x;
  const int l = tid & 63, w = tid >> 6;
  const int wm = w >> 2, wn = w & 3;
  const int fr = l & 15, fq = l >> 4;

  const ushort* Ab = A + (size_t)bm * 256 * K;
  const ushort* Bb = Bt + (size_t)bn * 256 * K;

  const int srow = (l >> 2);
  const int scol = (((l & 3) ^ ((l >> 2) & 3)) * 8);

  f32x4 acc[8][4];
#pragma unroll
  for (int m = 0; m < 8; m++)
#pragma unroll
    for (int n = 0; n < 4; n++) acc[m][n] = (f32x4)0.0f;

  const int NT = K >> 5;

#define STAGE256(t)                                                            \
  {                                                                            \
    const int b3 = (t) % 3;                                                    \
    const size_t kk = (size_t)(t) * 32;                                        \
    _Pragma("unroll") for (int i = 0; i < 2; i++) {                            \
      const int r = (w * 2 + i) * 16 + srow;                                   \
      gload_lds16(Ab + (size_t)r * K + kk + scol,                              \
                  &lds[b3 * 16384 + (w * 2 + i) * 512]);                       \
      gload_lds16(Bb + (size_t)r * K + kk + scol,                              \
                  &lds[b3 * 16384 + 8192 + (w * 2 + i) * 512]);                \
    }                                                                          \
  }

  STAGE256(0);
  STAGE256(1);

  for (int t = 0; t < NT; ++t) {
    if (t + 2 < NT) {
      STAGE256(t + 2);
      asm volatile("s_waitcnt vmcnt(8)" ::: "memory");
    } else if (t + 1 < NT) {
      asm volatile("s_waitcnt vmcnt(4)" ::: "memory");
    } else {
      asm volatile("s_waitcnt vmcnt(0)" ::: "memory");
    }
    __builtin_amdgcn_s_barrier();
    asm volatile("" ::: "memory");

    const ushort* La = &lds[(t % 3) * 16384];
    const ushort* Lb = La + 8192;

    bf16x8 af[8], bf[4];
#pragma unroll
    for (int m = 0; m < 8; m++) {
      const int r = wm * 128 + m * 16 + fr;
      af[m] = *(const bf16x8*)&La[r * 32 + ((fq ^ (r & 3)) * 8)];
    }
#pragma unroll
    for (int n = 0; n < 4; n++) {
      const int r = wn * 64 + n * 16 + fr;
      bf[n] = *(const bf16x8*)&Lb[r * 32 + ((fq ^ (r & 3)) * 8)];
    }

    __builtin_amdgcn_s_setprio(1);
#pragma unroll
    for (int m = 0; m < 8; m++)
#pragma unroll
      for (int n = 0; n < 4; n++)
        acc[m][n] = __builtin_amdgcn_mfma_f32_16x16x32_bf16(af[m], bf[n], acc[m][n], 0, 0, 0);
    __builtin_amdgcn_s_setprio(0);

    asm volatile("" ::: "memory");
    __builtin_amdgcn_s_barrier();
  }
#undef STAGE256

  const int rowb = bm * 256 + wm * 128 + fq * 4;
  const int colb = bn * 256 + wn * 64 + fr;
#pragma unroll
  for (int m = 0; m < 8; m++) {
#pragma unroll
    for (int n = 0; n < 4; n++) {
      const int col = colb + n * 16;
#pragma unroll
      for (int j = 0; j < 4; j++) {
        const int row = rowb + m * 16 + j;
        float vv = acc[m][n][j];
        if (MODE == 0) {
          Cb[(size_t)row * N + col] = f2b(vv);
        } else if (MODE == 2) {
          if (col < 1024) vv *= 0.125f;
          Cb[(size_t)row * N + col] = f2b(vv);
        } else {
          Cf[(size_t)row * N + col] = vv + bias[col] + res[(size_t)row * N + col];
        }
      }
    }
  }
}

// ---------------- GEGLU GEMM, gemm256-style pipeline --------------------------
// Output tile: 256 rows x 128 U-cols; dual acc (a,g) = 128 VGPR.
// LDS/stage: A 256x32 (16KB) + Ba 128x32 (8KB) + Bg 128x32 (8KB) = 32KB x3 = 96KB.
// Same 3-deep counted-vmcnt schedule as gemm256 (4 loads/thread/stage).
__global__ __launch_bounds__(512) void gemm_geglu_kernel(
    const ushort* __restrict__ A, const ushort* __restrict__ W1t,
    const float* __restrict__ b1, ushort* __restrict__ U) {
  const int K = 1024;
  __shared__ __align__(16) ushort lds[3 * 16384];  // 96 KB

  const int bn = blockIdx.x & 15;   // 2048/128 col tiles
  const int bm = blockIdx.x >> 4;
  const int tid = threadIdx.x;
  const int l = tid & 63, w = tid >> 6;
  const int wm = w >> 2, wn = w & 3;
  const int fr = l & 15, fq = l >> 4;

  const ushort* Ab = A + (size_t)bm * 256 * K;
  const ushort* Bab = W1t + (size_t)bn * 128 * K;
  const ushort* Bgb = W1t + (size_t)(2048 + bn * 128) * K;

  const int srow = (l >> 2);
  const int scol = (((l & 3) ^ ((l >> 2) & 3)) * 8);
  const int brow = (tid >> 2);                       // 0..127 (B rows)
  const int bscol = (((tid & 3) ^ ((tid >> 2) & 3)) * 8);

  f32x4 acca[8][2], accg[8][2];
#pragma unroll
  for (int m = 0; m < 8; m++)
#pragma unroll
    for (int n = 0; n < 2; n++) { acca[m][n] = (f32x4)0.0f; accg[m][n] = (f32x4)0.0f; }

  const int NT = K >> 5;  // 32

#define STAGEGL(t)                                                             \
  {                                                                            \
    const int b3 = (t) % 3;                                                    \
    const size_t kk = (size_t)(t) * 32;                                        \
    _Pragma("unroll") for (int i = 0; i < 2; i++) {                            \
      const int r = (w * 2 + i) * 16 + srow;                                   \
      gload_lds16(Ab + (size_t)r * K + kk + scol,                              \
                  &lds[b3 * 16384 + (w * 2 + i) * 512]);                       \
    }                                                                          \
    gload_lds16(Bab + (size_t)brow * K + kk + bscol,                           \
                &lds[b3 * 16384 + 8192 + w * 512]);                            \
    gload_lds16(Bgb + (size_t)brow * K + kk + bscol,                           \
                &lds[b3 * 16384 + 12288 + w * 512]);                           \
  }

  STAGEGL(0);
  STAGEGL(1);

  for (int t = 0; t < NT; ++t) {
    if (t + 2 < NT) {
      STAGEGL(t + 2);
      asm volatile("s_waitcnt vmcnt(8)" ::: "memory");
    } else if (t + 1 < NT) {
      asm volatile("s_waitcnt vmcnt(4)" ::: "memory");
    } else {
      asm volatile("s_waitcnt vmcnt(0)" ::: "memory");
    }
    __builtin_amdgcn_s_barrier();
    asm volatile("" ::: "memory");

    const ushort* La = &lds[(t % 3) * 16384];
    const ushort* Lba = La + 8192;
    const ushort* Lbg = La + 12288;

    bf16x8 af[8], ba[2], bg[2];
#pragma unroll
    for (int m = 0; m < 8; m++) {
      const int r = wm * 128 + m * 16 + fr;
      af[m] = *(const bf16x8*)&La[r * 32 + ((fq ^ (r & 3)) * 8)];
    }
#pragma unroll
    for (int n = 0; n < 2; n++) {
      const int r = wn * 32 + n * 16 + fr;
      ba[n] = *(const bf16x8*)&Lba[r * 32 + ((fq ^ (r & 3)) * 8)];
      bg[n] = *(const bf16x8*)&Lbg[r * 32 + ((fq ^ (r & 3)) * 8)];
    }

    __builtin_amdgcn_s_setprio(1);
#pragma unroll
    for (int m = 0; m < 8; m++)
#pragma unroll
      for (int n = 0; n < 2; n++) {
        acca[m][n] = __builtin_amdgcn_mfma_f32_16x16x32_bf16(af[m], ba[n], acca[m][n], 0, 0, 0);
        accg[m][n] = __builtin_amdgcn_mfma_f32_16x16x32_bf16(af[m], bg[n], accg[m][n], 0, 0, 0);
      }
    __builtin_amdgcn_s_setprio(0);

    asm volatile("" ::: "memory");
    __builtin_amdgcn_s_barrier();
  }
#undef STAGEGL

  const int rowb = bm * 256 + wm * 128 + fq * 4;
  const int colb = bn * 128 + wn * 32 + fr;
#pragma unroll
  for (int m = 0; m < 8; m++) {
#pragma unroll
    for (int n = 0; n < 2; n++) {
      const int col = colb + n * 16;
      const float b1a = b1[col];
      const float b1g = b1[2048 + col];
#pragma unroll
      for (int j = 0; j < 4; j++) {
        const int row = rowb + m * 16 + j;
        const float a = acca[m][n][j] + b1a;
        const float gg = accg[m][n][j] + b1g;
        U[(size_t)row * 2048 + col] = f2b(a * gelu_fast(gg));
      }
    }
  }
}

// ---------------- windowed causal attention (no-max online softmax) ----------
__global__ __launch_bounds__(256, 3) void attn_kernel(
    const ushort* __restrict__ Q, const ushort* __restrict__ Kb,
    const ushort* __restrict__ Vb, ushort* __restrict__ O, const int qs) {
  const int bx = blockIdx.x;
  const int n = bx & 15;
  const int h = (bx >> 4) & 15;
  const int b = bx >> 8;
  const int tid = threadIdx.x;
  const int lane = tid & 63, wv = tid >> 6;
  const int fr = lane & 15, fq = lane >> 4;

  __shared__ __align__(16) ushort Kl[64 * 72];
  __shared__ __align__(16) ushort Vt[64 * 70];
  __shared__ __align__(16) ushort Pl[4][64 * 68];

  const size_t qrow0 = (size_t)b * 4096 + (size_t)n * 256;

  bf16x8 qf[4][2];
#pragma unroll
  for (int m = 0; m < 4; m++)
#pragma unroll
    for (int kh = 0; kh < 2; kh++)
      qf[m][kh] = *(const bf16x8*)&Q[(qrow0 + wv * 64 + m * 16 + fr) * qs + h * 64 + kh * 32 + fq * 8];

  f32x4 oacc[4][4];
#pragma unroll
  for (int m = 0; m < 4; m++)
#pragma unroll
    for (int d = 0; d < 4; d++) oacc[m][d] = (f32x4)0.0f;

  float lsum[4][4];
#pragma unroll
  for (int m = 0; m < 4; m++)
#pragma unroll
    for (int j = 0; j < 4; j++) lsum[m][j] = 0.0f;

  const int c0 = (n == 0) ? 4 : 0;
  for (int c = c0; c < 8; c++) {
    const size_t kvrow0 =
        (size_t)((long long)b * 4096 + (long long)n * 256 + (long long)c * 64 - 256);
#pragma unroll
    for (int p = 0; p < 2; p++) {
      const int s = tid + p * 256;
      const int rr = s >> 3, cs2 = s & 7;
      *(u16x8*)&Kl[rr * 72 + cs2 * 8] =
          *(const u16x8*)&Kb[(kvrow0 + rr) * qs + h * 64 + cs2 * 8];
      const u16x8 vvv = *(const u16x8*)&Vb[(kvrow0 + rr) * qs + h * 64 + cs2 * 8];
#pragma unroll
      for (int i = 0; i < 8; i++) Vt[(cs2 * 8 + i) * 70 + rr] = vvv[i];
    }
    __syncthreads();

    if (c <= wv + 4) {
      const bool diag = (c == wv + 4);
#pragma unroll
      for (int nn = 0; nn < 4; nn++) {
        f32x4 sa[4];
#pragma unroll
        for (int m = 0; m < 4; m++) sa[m] = (f32x4)0.0f;
#pragma unroll
        for (int kh = 0; kh < 2; kh++) {
          const bf16x8 bk = *(const bf16x8*)&Kl[(nn * 16 + fr) * 72 + kh * 32 + fq * 8];
#pragma unroll
          for (int m = 0; m < 4; m++)
            sa[m] = __builtin_amdgcn_mfma_f32_16x16x32_bf16(qf[m][kh], bk, sa[m], 0, 0, 0);
        }
#pragma unroll
        for (int m = 0; m < 4; m++)
#pragma unroll
          for (int j = 0; j < 4; j++) {
            float p = __expf(sa[m][j]);
            if (diag && (nn * 16 + fr > m * 16 + fq * 4 + j)) p = 0.0f;
            lsum[m][j] += p;
            Pl[wv][(m * 16 + fq * 4 + j) * 68 + nn * 16 + fr] = f2b(p);
          }
      }
      __builtin_amdgcn_s_setprio(1);
#pragma unroll
      for (int kh = 0; kh < 2; kh++) {
        bf16x8 pa[4];
#pragma unroll
        for (int m = 0; m < 4; m++)
          pa[m] = *(const bf16x8*)&Pl[wv][(m * 16 + fr) * 68 + kh * 32 + fq * 8];
#pragma unroll
        for (int d = 0; d < 4; d++) {
          const bf16x8 vb = *(const bf16x8*)&Vt[(d * 16 + fr) * 70 + kh * 32 + fq * 8];
#pragma unroll
          for (int m = 0; m < 4; m++)
            oacc[m][d] = __builtin_amdgcn_mfma_f32_16x16x32_bf16(pa[m], vb, oacc[m][d], 0, 0, 0);
        }
      }
      __builtin_amdgcn_s_setprio(0);
    }
    __syncthreads();
  }

  float rl[4][4];
#pragma unroll
  for (int m = 0; m < 4; m++)
#pragma unroll
    for (int j = 0; j < 4; j++) {
      float t = lsum[m][j];
      t += __shfl_xor(t, 1);
      t += __shfl_xor(t, 2);
      t += __shfl_xor(t, 4);
      t += __shfl_xor(t, 8);
      rl[m][j] = 1.0f / t;
    }

#pragma unroll
  for (int m = 0; m < 4; m++)
#pragma unroll
    for (int d = 0; d < 4; d++)
#pragma unroll
      for (int j = 0; j < 4; j++) {
        const float o = oacc[m][d][j] * rl[m][j];
        O[(qrow0 + wv * 64 + m * 16 + fq * 4 + j) * 1024 + h * 64 + d * 16 + fr] = f2b(o);
      }
}

// ---------------- host launcher ----------------------------------------------
extern "C" void kernel_launch(void* const* d_in, const int* in_sizes, int n_in,
                              void* d_out, int out_size, void* d_ws, size_t ws_size,
                              hipStream_t stream) {
  (void)in_sizes; (void)n_in; (void)out_size; (void)ws_size;
  const float* x     = (const float*)d_in[0];
  const float* ln1_g = (const float*)d_in[1];
  const float* ln1_b = (const float*)d_in[2];
  const float* ln2_g = (const float*)d_in[3];
  const float* ln2_b = (const float*)d_in[4];
  const float* Wq    = (const float*)d_in[5];
  const float* Wk    = (const float*)d_in[6];
  const float* Wv    = (const float*)d_in[7];
  const float* Wo    = (const float*)d_in[8];
  const float* bo    = (const float*)d_in[9];
  const float* W1    = (const float*)d_in[10];
  const float* b1    = (const float*)d_in[11];
  const float* W2    = (const float*)d_in[12];
  const float* b2    = (const float*)d_in[13];

  char* ws = (char*)d_ws;
  const size_t MB = 1ull << 20;
  ushort* WQKVT = (ushort*)(ws + 0 * MB);   // [3072,1024]
  ushort* WOT = (ushort*)(ws + 6 * MB);     // [1024,1024]
  ushort* W1T = (ushort*)(ws + 8 * MB);     // [4096,1024]
  ushort* W2T = (ushort*)(ws + 16 * MB);    // [1024,2048]
  ushort* LN1 = (ushort*)(ws + 20 * MB);    // 32MB
  ushort* ATT = LN1;
  ushort* QKV = (ushort*)(ws + 52 * MB);    // [16384,3072] = 96MB
  ushort* LN2 = (ushort*)(ws + 52 * MB);
  ushort* U   = (ushort*)(ws + 84 * MB);    // 64MB
  float*  X1  = (float*)d_out;
  float*  OUT = (float*)d_out;

  const dim3 tb(32, 8);
  transpose_cast_kernel<<<dim3(32, 32), tb, 0, stream>>>(Wq, WQKVT, 1024, 1024);
  transpose_cast_kernel<<<dim3(32, 32), tb, 0, stream>>>(Wk, WQKVT + (size_t)1024 * 1024, 1024, 1024);
  transpose_cast_kernel<<<dim3(32, 32), tb, 0, stream>>>(Wv, WQKVT + (size_t)2048 * 1024, 1024, 1024);
  transpose_cast_kernel<<<dim3(32, 32), tb, 0, stream>>>(Wo, WOT, 1024, 1024);
  transpose_cast_kernel<<<dim3(128, 32), tb, 0, stream>>>(W1, W1T, 1024, 4096);
  transpose_cast_kernel<<<dim3(32, 64), tb, 0, stream>>>(W2, W2T, 2048, 1024);

  ln_kernel<<<16384, 256, 0, stream>>>(x, ln1_g, ln1_b, LN1);

  // fused QKV (Q pre-scaled by 1/8 in epilogue): [16384,3072]
  gemm256_kernel<2><<<64 * 12, 512, 0, stream>>>(LN1, WQKVT, 16384, 3072, 1024,
                                                 QKV, nullptr, nullptr, nullptr);

  attn_kernel<<<1024, 256, 0, stream>>>(QKV, QKV + 1024, QKV + 2048, ATT, 3072);

  // x1 = x + ATT*Wo^T + bo  (fp32, into d_out)
  gemm256_kernel<1><<<64 * 4, 512, 0, stream>>>(ATT, WOT, 16384, 1024, 1024,
                                                nullptr, X1, bo, x);

  ln_kernel<<<16384, 256, 0, stream>>>(X1, ln2_g, ln2_b, LN2);

  // U = a * gelu(g), 256x128 dual-acc pipelined
  gemm_geglu_kernel<<<64 * 16, 512, 0, stream>>>(LN2, W1T, b1, U);

  // out = x1 + U*W2^T + b2  (in-place on d_out)
  gemm256_kernel<1><<<64 * 4, 512, 0, stream>>>(U, W2T, 16384, 1024, 2048,
                                                nullptr, OUT, b2, X1);
}

// Round 8
// 556.956 us; speedup vs baseline: 1.7606x; 1.0302x over previous
//
#include <hip/hip_runtime.h>
#include <hip/hip_bf16.h>

typedef __attribute__((ext_vector_type(4))) float f32x4;
typedef __attribute__((ext_vector_type(8))) short bf16x8;
typedef __attribute__((ext_vector_type(8))) unsigned short u16x8;

static __device__ __forceinline__ ushort f2b(float f) {
  union { float f; unsigned u; } v; v.f = f;
  unsigned r = v.u + 0x7fffu + ((v.u >> 16) & 1u);
  return (ushort)(r >> 16);
}

static __device__ __forceinline__ float gelu_fast(float g) {
  const float c0 = 0.7978845608028654f, c1 = 0.044715f;
  const float u = c0 * (g + c1 * g * g * g);
  const float e = __expf(2.0f * u);
  const float t = 1.0f - 2.0f / (e + 1.0f);
  return 0.5f * g * (1.0f + t);
}

static __device__ __forceinline__ void gload_lds16(const void* g, void* l) {
  __builtin_amdgcn_global_load_lds(
      (__attribute__((address_space(1))) void*)(g),
      (__attribute__((address_space(3))) void*)(l), 16, 0, 0);
}

// ---------------- weight transpose + cast: Wt[n][k] = bf16(W[k][n]) -----------
__global__ __launch_bounds__(256) void transpose_cast_kernel(
    const float* __restrict__ W, ushort* __restrict__ Wt, int K, int N) {
  __shared__ float tile[32][33];
  const int n0 = blockIdx.x * 32, k0 = blockIdx.y * 32;
  const int tx = threadIdx.x, ty = threadIdx.y;  // 32 x 8
#pragma unroll
  for (int r = 0; r < 32; r += 8)
    tile[ty + r][tx] = W[(size_t)(k0 + ty + r) * N + n0 + tx];
  __syncthreads();
#pragma unroll
  for (int r = 0; r < 32; r += 8)
    Wt[(size_t)(n0 + ty + r) * K + k0 + tx] = f2b(tile[tx][ty + r]);
}

// ---------------- layernorm (rows of 1024 fp32) -> bf16 ----------------------
__global__ __launch_bounds__(256) void ln_kernel(
    const float* __restrict__ x, const float* __restrict__ g,
    const float* __restrict__ bb, ushort* __restrict__ out) {
  const int row = blockIdx.x;
  const float* xr = x + (size_t)row * 1024;
  const float4 v = *(const float4*)&xr[threadIdx.x * 4];
  float s = v.x + v.y + v.z + v.w;
  float s2 = v.x * v.x + v.y * v.y + v.z * v.z + v.w * v.w;
#pragma unroll
  for (int off = 32; off > 0; off >>= 1) {
    s += __shfl_down(s, off);
    s2 += __shfl_down(s2, off);
  }
  __shared__ float red[8];
  const int lane = threadIdx.x & 63, wv = threadIdx.x >> 6;
  if (lane == 0) { red[wv] = s; red[4 + wv] = s2; }
  __syncthreads();
  s = red[0] + red[1] + red[2] + red[3];
  s2 = red[4] + red[5] + red[6] + red[7];
  const float mu = s * (1.0f / 1024.0f);
  const float rs = rsqrtf(s2 * (1.0f / 1024.0f) - mu * mu + 1e-5f);
  const int c = threadIdx.x * 4;
  ushort4 o;
  o.x = f2b((v.x - mu) * rs * g[c + 0] + bb[c + 0]);
  o.y = f2b((v.y - mu) * rs * g[c + 1] + bb[c + 1]);
  o.z = f2b((v.z - mu) * rs * g[c + 2] + bb[c + 2]);
  o.w = f2b((v.w - mu) * rs * g[c + 3] + bb[c + 3]);
  *(ushort4*)&out[(size_t)row * 1024 + c] = o;
}

// ---------------- 256x256 deep-pipelined GEMM: C = A[M,K] * Bt[N,K]^T --------
// 512 threads = 8 waves (2 wm x 4 wn); per-wave 128x64 output.
// 3 LDS buffers (BK=32), counted vmcnt(8); both-sides XOR swizzle.
// Swizzle: slot s = fq ^ ((r>>1)&3). Row stride is 64B (16 banks), so row
// parity folds banks mod 32; XOR on r bits 1-2 gives even-row lanes all 4
// slots -> 2 lanes/bank (free) instead of 4-way with r&3.
template <int MODE>
__global__ __launch_bounds__(512) void gemm256_kernel(
    const ushort* __restrict__ A, const ushort* __restrict__ Bt,
    const int M, const int N, const int K,
    ushort* __restrict__ Cb, float* __restrict__ Cf,
    const float* __restrict__ bias, const float* __restrict__ res) {
  __shared__ __align__(16) ushort lds[3 * 16384];  // 96 KB

  const int ntn = N >> 8;
  const int bn = blockIdx.x % ntn;
  const int bm = blockIdx.x / ntn;
  const int tid = threadIdx.x;
  const int l = tid & 63, w = tid >> 6;
  const int wm = w >> 2, wn = w & 3;
  const int fr = l & 15, fq = l >> 4;

  const ushort* Ab = A + (size_t)bm * 256 * K;
  const ushort* Bb = Bt + (size_t)bn * 256 * K;

  const int srow = (l >> 2);
  const int scol = (((l & 3) ^ ((l >> 3) & 3)) * 8);  // inverse swizzle on source

  f32x4 acc[8][4];
#pragma unroll
  for (int m = 0; m < 8; m++)
#pragma unroll
    for (int n = 0; n < 4; n++) acc[m][n] = (f32x4)0.0f;

  const int NT = K >> 5;

#define STAGE256(t)                                                            \
  {                                                                            \
    const int b3 = (t) % 3;                                                    \
    const size_t kk = (size_t)(t) * 32;                                        \
    _Pragma("unroll") for (int i = 0; i < 2; i++) {                            \
      const int r = (w * 2 + i) * 16 + srow;                                   \
      gload_lds16(Ab + (size_t)r * K + kk + scol,                              \
                  &lds[b3 * 16384 + (w * 2 + i) * 512]);                       \
      gload_lds16(Bb + (size_t)r * K + kk + scol,                              \
                  &lds[b3 * 16384 + 8192 + (w * 2 + i) * 512]);                \
    }                                                                          \
  }

  STAGE256(0);
  STAGE256(1);

  for (int t = 0; t < NT; ++t) {
    if (t + 2 < NT) {
      STAGE256(t + 2);
      asm volatile("s_waitcnt vmcnt(8)" ::: "memory");
    } else if (t + 1 < NT) {
      asm volatile("s_waitcnt vmcnt(4)" ::: "memory");
    } else {
      asm volatile("s_waitcnt vmcnt(0)" ::: "memory");
    }
    __builtin_amdgcn_s_barrier();
    asm volatile("" ::: "memory");

    const ushort* La = &lds[(t % 3) * 16384];
    const ushort* Lb = La + 8192;

    bf16x8 af[8], bf[4];
#pragma unroll
    for (int m = 0; m < 8; m++) {
      const int r = wm * 128 + m * 16 + fr;
      af[m] = *(const bf16x8*)&La[r * 32 + ((fq ^ ((r >> 1) & 3)) * 8)];
    }
#pragma unroll
    for (int n = 0; n < 4; n++) {
      const int r = wn * 64 + n * 16 + fr;
      bf[n] = *(const bf16x8*)&Lb[r * 32 + ((fq ^ ((r >> 1) & 3)) * 8)];
    }

    __builtin_amdgcn_s_setprio(1);
#pragma unroll
    for (int m = 0; m < 8; m++)
#pragma unroll
      for (int n = 0; n < 4; n++)
        acc[m][n] = __builtin_amdgcn_mfma_f32_16x16x32_bf16(af[m], bf[n], acc[m][n], 0, 0, 0);
    __builtin_amdgcn_s_setprio(0);

    asm volatile("" ::: "memory");
    __builtin_amdgcn_s_barrier();
  }
#undef STAGE256

  const int rowb = bm * 256 + wm * 128 + fq * 4;
  const int colb = bn * 256 + wn * 64 + fr;
#pragma unroll
  for (int m = 0; m < 8; m++) {
#pragma unroll
    for (int n = 0; n < 4; n++) {
      const int col = colb + n * 16;
#pragma unroll
      for (int j = 0; j < 4; j++) {
        const int row = rowb + m * 16 + j;
        float vv = acc[m][n][j];
        if (MODE == 0) {
          Cb[(size_t)row * N + col] = f2b(vv);
        } else if (MODE == 2) {
          if (col < 1024) vv *= 0.125f;
          Cb[(size_t)row * N + col] = f2b(vv);
        } else {
          Cf[(size_t)row * N + col] = vv + bias[col] + res[(size_t)row * N + col];
        }
      }
    }
  }
}

// ---------------- GEGLU GEMM, gemm256-style pipeline --------------------------
// Output tile: 256 rows x 128 U-cols; dual acc (a,g) = 128 VGPR.
// Same 3-deep counted-vmcnt schedule and fixed swizzle as gemm256.
__global__ __launch_bounds__(512) void gemm_geglu_kernel(
    const ushort* __restrict__ A, const ushort* __restrict__ W1t,
    const float* __restrict__ b1, ushort* __restrict__ U) {
  const int K = 1024;
  __shared__ __align__(16) ushort lds[3 * 16384];  // 96 KB

  const int bn = blockIdx.x & 15;   // 2048/128 col tiles
  const int bm = blockIdx.x >> 4;
  const int tid = threadIdx.x;
  const int l = tid & 63, w = tid >> 6;
  const int wm = w >> 2, wn = w & 3;
  const int fr = l & 15, fq = l >> 4;

  const ushort* Ab = A + (size_t)bm * 256 * K;
  const ushort* Bab = W1t + (size_t)bn * 128 * K;
  const ushort* Bgb = W1t + (size_t)(2048 + bn * 128) * K;

  const int srow = (l >> 2);
  const int scol = (((l & 3) ^ ((l >> 3) & 3)) * 8);
  const int brow = (tid >> 2);                        // 0..127 (B rows)
  const int bscol = (((tid & 3) ^ ((tid >> 3) & 3)) * 8);

  f32x4 acca[8][2], accg[8][2];
#pragma unroll
  for (int m = 0; m < 8; m++)
#pragma unroll
    for (int n = 0; n < 2; n++) { acca[m][n] = (f32x4)0.0f; accg[m][n] = (f32x4)0.0f; }

  const int NT = K >> 5;  // 32

#define STAGEGL(t)                                                             \
  {                                                                            \
    const int b3 = (t) % 3;                                                    \
    const size_t kk = (size_t)(t) * 32;                                        \
    _Pragma("unroll") for (int i = 0; i < 2; i++) {                            \
      const int r = (w * 2 + i) * 16 + srow;                                   \
      gload_lds16(Ab + (size_t)r * K + kk + scol,                              \
                  &lds[b3 * 16384 + (w * 2 + i) * 512]);                       \
    }                                                                          \
    gload_lds16(Bab + (size_t)brow * K + kk + bscol,                           \
                &lds[b3 * 16384 + 8192 + w * 512]);                            \
    gload_lds16(Bgb + (size_t)brow * K + kk + bscol,                           \
                &lds[b3 * 16384 + 12288 + w * 512]);                           \
  }

  STAGEGL(0);
  STAGEGL(1);

  for (int t = 0; t < NT; ++t) {
    if (t + 2 < NT) {
      STAGEGL(t + 2);
      asm volatile("s_waitcnt vmcnt(8)" ::: "memory");
    } else if (t + 1 < NT) {
      asm volatile("s_waitcnt vmcnt(4)" ::: "memory");
    } else {
      asm volatile("s_waitcnt vmcnt(0)" ::: "memory");
    }
    __builtin_amdgcn_s_barrier();
    asm volatile("" ::: "memory");

    const ushort* La = &lds[(t % 3) * 16384];
    const ushort* Lba = La + 8192;
    const ushort* Lbg = La + 12288;

    bf16x8 af[8], ba[2], bg[2];
#pragma unroll
    for (int m = 0; m < 8; m++) {
      const int r = wm * 128 + m * 16 + fr;
      af[m] = *(const bf16x8*)&La[r * 32 + ((fq ^ ((r >> 1) & 3)) * 8)];
    }
#pragma unroll
    for (int n = 0; n < 2; n++) {
      const int r = wn * 32 + n * 16 + fr;
      ba[n] = *(const bf16x8*)&Lba[r * 32 + ((fq ^ ((r >> 1) & 3)) * 8)];
      bg[n] = *(const bf16x8*)&Lbg[r * 32 + ((fq ^ ((r >> 1) & 3)) * 8)];
    }

    __builtin_amdgcn_s_setprio(1);
#pragma unroll
    for (int m = 0; m < 8; m++)
#pragma unroll
      for (int n = 0; n < 2; n++) {
        acca[m][n] = __builtin_amdgcn_mfma_f32_16x16x32_bf16(af[m], ba[n], acca[m][n], 0, 0, 0);
        accg[m][n] = __builtin_amdgcn_mfma_f32_16x16x32_bf16(af[m], bg[n], accg[m][n], 0, 0, 0);
      }
    __builtin_amdgcn_s_setprio(0);

    asm volatile("" ::: "memory");
    __builtin_amdgcn_s_barrier();
  }
#undef STAGEGL

  const int rowb = bm * 256 + wm * 128 + fq * 4;
  const int colb = bn * 128 + wn * 32 + fr;
#pragma unroll
  for (int m = 0; m < 8; m++) {
#pragma unroll
    for (int n = 0; n < 2; n++) {
      const int col = colb + n * 16;
      const float b1a = b1[col];
      const float b1g = b1[2048 + col];
#pragma unroll
      for (int j = 0; j < 4; j++) {
        const int row = rowb + m * 16 + j;
        const float a = acca[m][n][j] + b1a;
        const float gg = accg[m][n][j] + b1g;
        U[(size_t)row * 2048 + col] = f2b(a * gelu_fast(gg));
      }
    }
  }
}

// ---------------- windowed causal attention (no-max online softmax) ----------
__global__ __launch_bounds__(256, 3) void attn_kernel(
    const ushort* __restrict__ Q, const ushort* __restrict__ Kb,
    const ushort* __restrict__ Vb, ushort* __restrict__ O, const int qs) {
  const int bx = blockIdx.x;
  const int n = bx & 15;
  const int h = (bx >> 4) & 15;
  const int b = bx >> 8;
  const int tid = threadIdx.x;
  const int lane = tid & 63, wv = tid >> 6;
  const int fr = lane & 15, fq = lane >> 4;

  __shared__ __align__(16) ushort Kl[64 * 72];
  __shared__ __align__(16) ushort Vt[64 * 70];
  __shared__ __align__(16) ushort Pl[4][64 * 68];

  const size_t qrow0 = (size_t)b * 4096 + (size_t)n * 256;

  bf16x8 qf[4][2];
#pragma unroll
  for (int m = 0; m < 4; m++)
#pragma unroll
    for (int kh = 0; kh < 2; kh++)
      qf[m][kh] = *(const bf16x8*)&Q[(qrow0 + wv * 64 + m * 16 + fr) * qs + h * 64 + kh * 32 + fq * 8];

  f32x4 oacc[4][4];
#pragma unroll
  for (int m = 0; m < 4; m++)
#pragma unroll
    for (int d = 0; d < 4; d++) oacc[m][d] = (f32x4)0.0f;

  float lsum[4][4];
#pragma unroll
  for (int m = 0; m < 4; m++)
#pragma unroll
    for (int j = 0; j < 4; j++) lsum[m][j] = 0.0f;

  const int c0 = (n == 0) ? 4 : 0;
  for (int c = c0; c < 8; c++) {
    const size_t kvrow0 =
        (size_t)((long long)b * 4096 + (long long)n * 256 + (long long)c * 64 - 256);
#pragma unroll
    for (int p = 0; p < 2; p++) {
      const int s = tid + p * 256;
      const int rr = s >> 3, cs2 = s & 7;
      *(u16x8*)&Kl[rr * 72 + cs2 * 8] =
          *(const u16x8*)&Kb[(kvrow0 + rr) * qs + h * 64 + cs2 * 8];
      const u16x8 vvv = *(const u16x8*)&Vb[(kvrow0 + rr) * qs + h * 64 + cs2 * 8];
#pragma unroll
      for (int i = 0; i < 8; i++) Vt[(cs2 * 8 + i) * 70 + rr] = vvv[i];
    }
    __syncthreads();

    if (c <= wv + 4) {
      const bool diag = (c == wv + 4);
#pragma unroll
      for (int nn = 0; nn < 4; nn++) {
        f32x4 sa[4];
#pragma unroll
        for (int m = 0; m < 4; m++) sa[m] = (f32x4)0.0f;
#pragma unroll
        for (int kh = 0; kh < 2; kh++) {
          const bf16x8 bk = *(const bf16x8*)&Kl[(nn * 16 + fr) * 72 + kh * 32 + fq * 8];
#pragma unroll
          for (int m = 0; m < 4; m++)
            sa[m] = __builtin_amdgcn_mfma_f32_16x16x32_bf16(qf[m][kh], bk, sa[m], 0, 0, 0);
        }
#pragma unroll
        for (int m = 0; m < 4; m++)
#pragma unroll
          for (int j = 0; j < 4; j++) {
            float p = __expf(sa[m][j]);
            if (diag && (nn * 16 + fr > m * 16 + fq * 4 + j)) p = 0.0f;
            lsum[m][j] += p;
            Pl[wv][(m * 16 + fq * 4 + j) * 68 + nn * 16 + fr] = f2b(p);
          }
      }
      __builtin_amdgcn_s_setprio(1);
#pragma unroll
      for (int kh = 0; kh < 2; kh++) {
        bf16x8 pa[4];
#pragma unroll
        for (int m = 0; m < 4; m++)
          pa[m] = *(const bf16x8*)&Pl[wv][(m * 16 + fr) * 68 + kh * 32 + fq * 8];
#pragma unroll
        for (int d = 0; d < 4; d++) {
          const bf16x8 vb = *(const bf16x8*)&Vt[(d * 16 + fr) * 70 + kh * 32 + fq * 8];
#pragma unroll
          for (int m = 0; m < 4; m++)
            oacc[m][d] = __builtin_amdgcn_mfma_f32_16x16x32_bf16(pa[m], vb, oacc[m][d], 0, 0, 0);
        }
      }
      __builtin_amdgcn_s_setprio(0);
    }
    __syncthreads();
  }

  float rl[4][4];
#pragma unroll
  for (int m = 0; m < 4; m++)
#pragma unroll
    for (int j = 0; j < 4; j++) {
      float t = lsum[m][j];
      t += __shfl_xor(t, 1);
      t += __shfl_xor(t, 2);
      t += __shfl_xor(t, 4);
      t += __shfl_xor(t, 8);
      rl[m][j] = 1.0f / t;
    }

#pragma unroll
  for (int m = 0; m < 4; m++)
#pragma unroll
    for (int d = 0; d < 4; d++)
#pragma unroll
      for (int j = 0; j < 4; j++) {
        const float o = oacc[m][d][j] * rl[m][j];
        O[(qrow0 + wv * 64 + m * 16 + fq * 4 + j) * 1024 + h * 64 + d * 16 + fr] = f2b(o);
      }
}

// ---------------- host launcher ----------------------------------------------
extern "C" void kernel_launch(void* const* d_in, const int* in_sizes, int n_in,
                              void* d_out, int out_size, void* d_ws, size_t ws_size,
                              hipStream_t stream) {
  (void)in_sizes; (void)n_in; (void)out_size; (void)ws_size;
  const float* x     = (const float*)d_in[0];
  const float* ln1_g = (const float*)d_in[1];
  const float* ln1_b = (const float*)d_in[2];
  const float* ln2_g = (const float*)d_in[3];
  const float* ln2_b = (const float*)d_in[4];
  const float* Wq    = (const float*)d_in[5];
  const float* Wk    = (const float*)d_in[6];
  const float* Wv    = (const float*)d_in[7];
  const float* Wo    = (const float*)d_in[8];
  const float* bo    = (const float*)d_in[9];
  const float* W1    = (const float*)d_in[10];
  const float* b1    = (const float*)d_in[11];
  const float* W2    = (const float*)d_in[12];
  const float* b2    = (const float*)d_in[13];

  char* ws = (char*)d_ws;
  const size_t MB = 1ull << 20;
  ushort* WQKVT = (ushort*)(ws + 0 * MB);   // [3072,1024]
  ushort* WOT = (ushort*)(ws + 6 * MB);     // [1024,1024]
  ushort* W1T = (ushort*)(ws + 8 * MB);     // [4096,1024]
  ushort* W2T = (ushort*)(ws + 16 * MB);    // [1024,2048]
  ushort* LN1 = (ushort*)(ws + 20 * MB);    // 32MB
  ushort* ATT = LN1;
  ushort* QKV = (ushort*)(ws + 52 * MB);    // [16384,3072] = 96MB
  ushort* LN2 = (ushort*)(ws + 52 * MB);
  ushort* U   = (ushort*)(ws + 84 * MB);    // 64MB
  float*  X1  = (float*)d_out;
  float*  OUT = (float*)d_out;

  const dim3 tb(32, 8);
  transpose_cast_kernel<<<dim3(32, 32), tb, 0, stream>>>(Wq, WQKVT, 1024, 1024);
  transpose_cast_kernel<<<dim3(32, 32), tb, 0, stream>>>(Wk, WQKVT + (size_t)1024 * 1024, 1024, 1024);
  transpose_cast_kernel<<<dim3(32, 32), tb, 0, stream>>>(Wv, WQKVT + (size_t)2048 * 1024, 1024, 1024);
  transpose_cast_kernel<<<dim3(32, 32), tb, 0, stream>>>(Wo, WOT, 1024, 1024);
  transpose_cast_kernel<<<dim3(128, 32), tb, 0, stream>>>(W1, W1T, 1024, 4096);
  transpose_cast_kernel<<<dim3(32, 64), tb, 0, stream>>>(W2, W2T, 2048, 1024);

  ln_kernel<<<16384, 256, 0, stream>>>(x, ln1_g, ln1_b, LN1);

  // fused QKV (Q pre-scaled by 1/8 in epilogue): [16384,3072]
  gemm256_kernel<2><<<64 * 12, 512, 0, stream>>>(LN1, WQKVT, 16384, 3072, 1024,
                                                 QKV, nullptr, nullptr, nullptr);

  attn_kernel<<<1024, 256, 0, stream>>>(QKV, QKV + 1024, QKV + 2048, ATT, 3072);

  // x1 = x + ATT*Wo^T + bo  (fp32, into d_out)
  gemm256_kernel<1><<<64 * 4, 512, 0, stream>>>(ATT, WOT, 16384, 1024, 1024,
                                                nullptr, X1, bo, x);

  ln_kernel<<<16384, 256, 0, stream>>>(X1, ln2_g, ln2_b, LN2);

  // U = a * gelu(g), 256x128 dual-acc pipelined
  gemm_geglu_kernel<<<64 * 16, 512, 0, stream>>>(LN2, W1T, b1, U);

  // out = x1 + U*W2^T + b2  (in-place on d_out)
  gemm256_kernel<1><<<64 * 4, 512, 0, stream>>>(U, W2T, 16384, 1024, 2048,
                                                nullptr, OUT, b2, X1);
}

// Round 9
// 535.716 us; speedup vs baseline: 1.8304x; 1.0396x over previous
//
#include <hip/hip_runtime.h>
#include <hip/hip_bf16.h>

typedef __attribute__((ext_vector_type(4))) float f32x4;
typedef __attribute__((ext_vector_type(8))) short bf16x8;
typedef __attribute__((ext_vector_type(8))) unsigned short u16x8;

static __device__ __forceinline__ ushort f2b(float f) {
  union { float f; unsigned u; } v; v.f = f;
  unsigned r = v.u + 0x7fffu + ((v.u >> 16) & 1u);
  return (ushort)(r >> 16);
}

static __device__ __forceinline__ float gelu_fast(float g) {
  const float c0 = 0.7978845608028654f, c1 = 0.044715f;
  const float u = c0 * (g + c1 * g * g * g);
  const float e = __expf(2.0f * u);
  const float t = 1.0f - 2.0f / (e + 1.0f);
  return 0.5f * g * (1.0f + t);
}

static __device__ __forceinline__ void gload_lds16(const void* g, void* l) {
  __builtin_amdgcn_global_load_lds(
      (__attribute__((address_space(1))) void*)(g),
      (__attribute__((address_space(3))) void*)(l), 16, 0, 0);
}

#define MFMA_BF16 __builtin_amdgcn_mfma_f32_16x16x32_bf16

// ---------------- weight transpose + cast: Wt[n][k] = bf16(W[k][n]) -----------
__global__ __launch_bounds__(256) void transpose_cast_kernel(
    const float* __restrict__ W, ushort* __restrict__ Wt, int K, int N) {
  __shared__ float tile[32][33];
  const int n0 = blockIdx.x * 32, k0 = blockIdx.y * 32;
  const int tx = threadIdx.x, ty = threadIdx.y;  // 32 x 8
#pragma unroll
  for (int r = 0; r < 32; r += 8)
    tile[ty + r][tx] = W[(size_t)(k0 + ty + r) * N + n0 + tx];
  __syncthreads();
#pragma unroll
  for (int r = 0; r < 32; r += 8)
    Wt[(size_t)(n0 + ty + r) * K + k0 + tx] = f2b(tile[tx][ty + r]);
}

// ---------------- layernorm (rows of 1024 fp32) -> bf16 ----------------------
__global__ __launch_bounds__(256) void ln_kernel(
    const float* __restrict__ x, const float* __restrict__ g,
    const float* __restrict__ bb, ushort* __restrict__ out) {
  const int row = blockIdx.x;
  const float* xr = x + (size_t)row * 1024;
  const float4 v = *(const float4*)&xr[threadIdx.x * 4];
  float s = v.x + v.y + v.z + v.w;
  float s2 = v.x * v.x + v.y * v.y + v.z * v.z + v.w * v.w;
#pragma unroll
  for (int off = 32; off > 0; off >>= 1) {
    s += __shfl_down(s, off);
    s2 += __shfl_down(s2, off);
  }
  __shared__ float red[8];
  const int lane = threadIdx.x & 63, wv = threadIdx.x >> 6;
  if (lane == 0) { red[wv] = s; red[4 + wv] = s2; }
  __syncthreads();
  s = red[0] + red[1] + red[2] + red[3];
  s2 = red[4] + red[5] + red[6] + red[7];
  const float mu = s * (1.0f / 1024.0f);
  const float rs = rsqrtf(s2 * (1.0f / 1024.0f) - mu * mu + 1e-5f);
  const int c = threadIdx.x * 4;
  ushort4 o;
  o.x = f2b((v.x - mu) * rs * g[c + 0] + bb[c + 0]);
  o.y = f2b((v.y - mu) * rs * g[c + 1] + bb[c + 1]);
  o.z = f2b((v.z - mu) * rs * g[c + 2] + bb[c + 2]);
  o.w = f2b((v.w - mu) * rs * g[c + 3] + bb[c + 3]);
  *(ushort4*)&out[(size_t)row * 1024 + c] = o;
}

// ---------------- 256x256 8-phase GEMM: C = A[M,K] * Bt[N,K]^T ---------------
// 512 thr = 8 waves (2 wm x 4 wn), per-wave 128x64 out. BK=64, double-buffered
// 128KB LDS. Per K-tile: 4 phases, each {stage 1 half-tile of t+1; (ph0:
// vmcnt(2) publish + barrier); ds_read subtile; barrier; setprio+16 MFMA;
// barrier}. One counted vmcnt per tile; <=8 loads in flight across barriers.
// Swizzle (128B rows): slot (kk*4+fq)^(r&7); source pre-swizzled, dest linear.
template <int MODE>
__global__ __launch_bounds__(512) void gemm256_kernel(
    const ushort* __restrict__ A, const ushort* __restrict__ Bt,
    const int M, const int N, const int K,
    ushort* __restrict__ Cb, float* __restrict__ Cf,
    const float* __restrict__ bias, const float* __restrict__ res) {
  __shared__ __align__(16) ushort lds[2 * 32768];  // 2 x (A 32KB + B 32KB) = 128KB

  const int ntn = N >> 8;
  const int bn = blockIdx.x % ntn;
  const int bm = blockIdx.x / ntn;
  const int tid = threadIdx.x;
  const int l = tid & 63, w = tid >> 6;
  const int wm = w >> 2, wn = w & 3;
  const int fr = l & 15, fq = l >> 4;

  const ushort* Ab = A + (size_t)bm * 256 * K;
  const ushort* Bb = Bt + (size_t)bn * 256 * K;

  const int lr = l >> 3;                              // lane row 0..7
  const int sc = (((l & 7) ^ lr) * 8);                // pre-swizzled src col

  f32x4 acc[8][4];
#pragma unroll
  for (int m = 0; m < 8; m++)
#pragma unroll
    for (int n = 0; n < 4; n++) acc[m][n] = (f32x4)0.0f;

  const int NT = K >> 6;

#define STG_A(h, tt)                                                           \
  { _Pragma("unroll") for (int i = 0; i < 2; i++) {                            \
      const int rr = (h) * 128 + i * 64 + w * 8;                               \
      gload_lds16(Ab + (size_t)(rr + lr) * K + (size_t)(tt) * 64 + sc,         \
                  &lds[((tt) & 1) * 32768 + rr * 64]); } }
#define STG_B(h, tt)                                                           \
  { _Pragma("unroll") for (int i = 0; i < 2; i++) {                            \
      const int rr = (h) * 128 + i * 64 + w * 8;                               \
      gload_lds16(Bb + (size_t)(rr + lr) * K + (size_t)(tt) * 64 + sc,         \
                  &lds[((tt) & 1) * 32768 + 16384 + rr * 64]); } }

  STG_A(0, 0); STG_A(1, 0); STG_B(0, 0); STG_B(1, 0);

  for (int t = 0; t < NT; ++t) {
    const ushort* La = &lds[(t & 1) * 32768];
    const ushort* Lb = La + 16384;
    bf16x8 af[4][2], bf[4][2];

    // ---- phase 0: publish tile t; MFMA m0-3 x n0-1
    if (t + 1 < NT) {
      STG_A(0, t + 1);
      asm volatile("s_waitcnt vmcnt(2)" ::: "memory");
    } else {
      asm volatile("s_waitcnt vmcnt(0)" ::: "memory");
    }
    __builtin_amdgcn_s_barrier();
    asm volatile("" ::: "memory");
#pragma unroll
    for (int m = 0; m < 4; m++) {
      const int r = wm * 128 + m * 16 + fr;
#pragma unroll
      for (int kk = 0; kk < 2; kk++)
        af[m][kk] = *(const bf16x8*)&La[r * 64 + (((kk * 4 + fq) ^ (r & 7)) * 8)];
    }
#pragma unroll
    for (int n = 0; n < 2; n++) {
      const int r = wn * 64 + n * 16 + fr;
#pragma unroll
      for (int kk = 0; kk < 2; kk++)
        bf[n][kk] = *(const bf16x8*)&Lb[r * 64 + (((kk * 4 + fq) ^ (r & 7)) * 8)];
    }
    __builtin_amdgcn_s_setprio(1);
#pragma unroll
    for (int m = 0; m < 4; m++)
#pragma unroll
      for (int n = 0; n < 2; n++)
#pragma unroll
        for (int kk = 0; kk < 2; kk++)
          acc[m][n] = MFMA_BF16(af[m][kk], bf[n][kk], acc[m][n], 0, 0, 0);
    __builtin_amdgcn_s_setprio(0);
    asm volatile("" ::: "memory");
    __builtin_amdgcn_s_barrier();

    // ---- phase 1: MFMA m0-3 x n2-3
    if (t + 1 < NT) STG_A(1, t + 1);
#pragma unroll
    for (int n = 2; n < 4; n++) {
      const int r = wn * 64 + n * 16 + fr;
#pragma unroll
      for (int kk = 0; kk < 2; kk++)
        bf[n][kk] = *(const bf16x8*)&Lb[r * 64 + (((kk * 4 + fq) ^ (r & 7)) * 8)];
    }
    __builtin_amdgcn_s_barrier();
    asm volatile("" ::: "memory");
    __builtin_amdgcn_s_setprio(1);
#pragma unroll
    for (int m = 0; m < 4; m++)
#pragma unroll
      for (int n = 2; n < 4; n++)
#pragma unroll
        for (int kk = 0; kk < 2; kk++)
          acc[m][n] = MFMA_BF16(af[m][kk], bf[n][kk], acc[m][n], 0, 0, 0);
    __builtin_amdgcn_s_setprio(0);
    asm volatile("" ::: "memory");
    __builtin_amdgcn_s_barrier();

    // ---- phase 2: MFMA m4-7 x n0-1
    if (t + 1 < NT) STG_B(0, t + 1);
#pragma unroll
    for (int m = 0; m < 4; m++) {
      const int r = wm * 128 + (m + 4) * 16 + fr;
#pragma unroll
      for (int kk = 0; kk < 2; kk++)
        af[m][kk] = *(const bf16x8*)&La[r * 64 + (((kk * 4 + fq) ^ (r & 7)) * 8)];
    }
    __builtin_amdgcn_s_barrier();
    asm volatile("" ::: "memory");
    __builtin_amdgcn_s_setprio(1);
#pragma unroll
    for (int m = 0; m < 4; m++)
#pragma unroll
      for (int n = 0; n < 2; n++)
#pragma unroll
        for (int kk = 0; kk < 2; kk++)
          acc[m + 4][n] = MFMA_BF16(af[m][kk], bf[n][kk], acc[m + 4][n], 0, 0, 0);
    __builtin_amdgcn_s_setprio(0);
    asm volatile("" ::: "memory");
    __builtin_amdgcn_s_barrier();

    // ---- phase 3: MFMA m4-7 x n2-3
    if (t + 1 < NT) STG_B(1, t + 1);
    __builtin_amdgcn_s_barrier();
    asm volatile("" ::: "memory");
    __builtin_amdgcn_s_setprio(1);
#pragma unroll
    for (int m = 0; m < 4; m++)
#pragma unroll
      for (int n = 2; n < 4; n++)
#pragma unroll
        for (int kk = 0; kk < 2; kk++)
          acc[m + 4][n] = MFMA_BF16(af[m][kk], bf[n][kk], acc[m + 4][n], 0, 0, 0);
    __builtin_amdgcn_s_setprio(0);
    asm volatile("" ::: "memory");
    __builtin_amdgcn_s_barrier();
  }
#undef STG_A
#undef STG_B

  const int rowb = bm * 256 + wm * 128 + fq * 4;
  const int colb = bn * 256 + wn * 64 + fr;
#pragma unroll
  for (int m = 0; m < 8; m++) {
#pragma unroll
    for (int n = 0; n < 4; n++) {
      const int col = colb + n * 16;
#pragma unroll
      for (int j = 0; j < 4; j++) {
        const int row = rowb + m * 16 + j;
        float vv = acc[m][n][j];
        if (MODE == 0) {
          Cb[(size_t)row * N + col] = f2b(vv);
        } else if (MODE == 2) {
          if (col < 1024) vv *= 0.125f;
          Cb[(size_t)row * N + col] = f2b(vv);
        } else {
          Cf[(size_t)row * N + col] = vv + bias[col] + res[(size_t)row * N + col];
        }
      }
    }
  }
}

// ---------------- GEGLU GEMM, 8-phase pipeline --------------------------------
// 256 rows x 128 U-cols; dual acc (a,g). LDS/buf: A 32KB + Ba 16KB + Bg 16KB,
// x2 = 128KB. Phases: {a m0-3, g m0-3, a m4-7, g m4-7}; staging {Ah0,Ah1,Ba,Bg}.
__global__ __launch_bounds__(512) void gemm_geglu_kernel(
    const ushort* __restrict__ A, const ushort* __restrict__ W1t,
    const float* __restrict__ b1, ushort* __restrict__ U) {
  const int K = 1024;
  __shared__ __align__(16) ushort lds[2 * 32768];  // 128 KB

  const int bn = blockIdx.x & 15;   // 2048/128 col tiles
  const int bm = blockIdx.x >> 4;
  const int tid = threadIdx.x;
  const int l = tid & 63, w = tid >> 6;
  const int wm = w >> 2, wn = w & 3;
  const int fr = l & 15, fq = l >> 4;

  const ushort* Ab = A + (size_t)bm * 256 * K;
  const ushort* Bab = W1t + (size_t)bn * 128 * K;
  const ushort* Bgb = W1t + (size_t)(2048 + bn * 128) * K;

  const int lr = l >> 3;
  const int sc = (((l & 7) ^ lr) * 8);

  f32x4 acca[8][2], accg[8][2];
#pragma unroll
  for (int m = 0; m < 8; m++)
#pragma unroll
    for (int n = 0; n < 2; n++) { acca[m][n] = (f32x4)0.0f; accg[m][n] = (f32x4)0.0f; }

  const int NT = K >> 6;  // 16

#define STG_GA(h, tt)                                                          \
  { _Pragma("unroll") for (int i = 0; i < 2; i++) {                            \
      const int rr = (h) * 128 + i * 64 + w * 8;                               \
      gload_lds16(Ab + (size_t)(rr + lr) * K + (size_t)(tt) * 64 + sc,         \
                  &lds[((tt) & 1) * 32768 + rr * 64]); } }
#define STG_BA(tt)                                                             \
  { _Pragma("unroll") for (int i = 0; i < 2; i++) {                            \
      const int rr = i * 64 + w * 8;                                           \
      gload_lds16(Bab + (size_t)(rr + lr) * K + (size_t)(tt) * 64 + sc,        \
                  &lds[((tt) & 1) * 32768 + 16384 + rr * 64]); } }
#define STG_BG(tt)                                                             \
  { _Pragma("unroll") for (int i = 0; i < 2; i++) {                            \
      const int rr = i * 64 + w * 8;                                           \
      gload_lds16(Bgb + (size_t)(rr + lr) * K + (size_t)(tt) * 64 + sc,        \
                  &lds[((tt) & 1) * 32768 + 24576 + rr * 64]); } }

  STG_GA(0, 0); STG_GA(1, 0); STG_BA(0); STG_BG(0);

  for (int t = 0; t < NT; ++t) {
    const ushort* La = &lds[(t & 1) * 32768];
    const ushort* Lba = La + 16384;
    const ushort* Lbg = La + 24576;
    bf16x8 af[4][2], ba[2][2], bg[2][2];

    // ---- phase 0: publish; a-MFMA m0-3
    if (t + 1 < NT) {
      STG_GA(0, t + 1);
      asm volatile("s_waitcnt vmcnt(2)" ::: "memory");
    } else {
      asm volatile("s_waitcnt vmcnt(0)" ::: "memory");
    }
    __builtin_amdgcn_s_barrier();
    asm volatile("" ::: "memory");
#pragma unroll
    for (int m = 0; m < 4; m++) {
      const int r = wm * 128 + m * 16 + fr;
#pragma unroll
      for (int kk = 0; kk < 2; kk++)
        af[m][kk] = *(const bf16x8*)&La[r * 64 + (((kk * 4 + fq) ^ (r & 7)) * 8)];
    }
#pragma unroll
    for (int n = 0; n < 2; n++) {
      const int r = wn * 32 + n * 16 + fr;
#pragma unroll
      for (int kk = 0; kk < 2; kk++)
        ba[n][kk] = *(const bf16x8*)&Lba[r * 64 + (((kk * 4 + fq) ^ (r & 7)) * 8)];
    }
    __builtin_amdgcn_s_setprio(1);
#pragma unroll
    for (int m = 0; m < 4; m++)
#pragma unroll
      for (int n = 0; n < 2; n++)
#pragma unroll
        for (int kk = 0; kk < 2; kk++)
          acca[m][n] = MFMA_BF16(af[m][kk], ba[n][kk], acca[m][n], 0, 0, 0);
    __builtin_amdgcn_s_setprio(0);
    asm volatile("" ::: "memory");
    __builtin_amdgcn_s_barrier();

    // ---- phase 1: g-MFMA m0-3
    if (t + 1 < NT) STG_GA(1, t + 1);
#pragma unroll
    for (int n = 0; n < 2; n++) {
      const int r = wn * 32 + n * 16 + fr;
#pragma unroll
      for (int kk = 0; kk < 2; kk++)
        bg[n][kk] = *(const bf16x8*)&Lbg[r * 64 + (((kk * 4 + fq) ^ (r & 7)) * 8)];
    }
    __builtin_amdgcn_s_barrier();
    asm volatile("" ::: "memory");
    __builtin_amdgcn_s_setprio(1);
#pragma unroll
    for (int m = 0; m < 4; m++)
#pragma unroll
      for (int n = 0; n < 2; n++)
#pragma unroll
        for (int kk = 0; kk < 2; kk++)
          accg[m][n] = MFMA_BF16(af[m][kk], bg[n][kk], accg[m][n], 0, 0, 0);
    __builtin_amdgcn_s_setprio(0);
    asm volatile("" ::: "memory");
    __builtin_amdgcn_s_barrier();

    // ---- phase 2: a-MFMA m4-7
    if (t + 1 < NT) STG_BA(t + 1);
#pragma unroll
    for (int m = 0; m < 4; m++) {
      const int r = wm * 128 + (m + 4) * 16 + fr;
#pragma unroll
      for (int kk = 0; kk < 2; kk++)
        af[m][kk] = *(const bf16x8*)&La[r * 64 + (((kk * 4 + fq) ^ (r & 7)) * 8)];
    }
    __builtin_amdgcn_s_barrier();
    asm volatile("" ::: "memory");
    __builtin_amdgcn_s_setprio(1);
#pragma unroll
    for (int m = 0; m < 4; m++)
#pragma unroll
      for (int n = 0; n < 2; n++)
#pragma unroll
        for (int kk = 0; kk < 2; kk++)
          acca[m + 4][n] = MFMA_BF16(af[m][kk], ba[n][kk], acca[m + 4][n], 0, 0, 0);
    __builtin_amdgcn_s_setprio(0);
    asm volatile("" ::: "memory");
    __builtin_amdgcn_s_barrier();

    // ---- phase 3: g-MFMA m4-7
    if (t + 1 < NT) STG_BG(t + 1);
    __builtin_amdgcn_s_barrier();
    asm volatile("" ::: "memory");
    __builtin_amdgcn_s_setprio(1);
#pragma unroll
    for (int m = 0; m < 4; m++)
#pragma unroll
      for (int n = 0; n < 2; n++)
#pragma unroll
        for (int kk = 0; kk < 2; kk++)
          accg[m + 4][n] = MFMA_BF16(af[m][kk], bg[n][kk], accg[m + 4][n], 0, 0, 0);
    __builtin_amdgcn_s_setprio(0);
    asm volatile("" ::: "memory");
    __builtin_amdgcn_s_barrier();
  }
#undef STG_GA
#undef STG_BA
#undef STG_BG

  const int rowb = bm * 256 + wm * 128 + fq * 4;
  const int colb = bn * 128 + wn * 32 + fr;
#pragma unroll
  for (int m = 0; m < 8; m++) {
#pragma unroll
    for (int n = 0; n < 2; n++) {
      const int col = colb + n * 16;
      const float b1a = b1[col];
      const float b1g = b1[2048 + col];
#pragma unroll
      for (int j = 0; j < 4; j++) {
        const int row = rowb + m * 16 + j;
        const float a = acca[m][n][j] + b1a;
        const float gg = accg[m][n][j] + b1g;
        U[(size_t)row * 2048 + col] = f2b(a * gelu_fast(gg));
      }
    }
  }
}

// ---------------- windowed causal attention (no-max online softmax) ----------
__global__ __launch_bounds__(256, 3) void attn_kernel(
    const ushort* __restrict__ Q, const ushort* __restrict__ Kb,
    const ushort* __restrict__ Vb, ushort* __restrict__ O, const int qs) {
  const int bx = blockIdx.x;
  const int n = bx & 15;
  const int h = (bx >> 4) & 15;
  const int b = bx >> 8;
  const int tid = threadIdx.x;
  const int lane = tid & 63, wv = tid >> 6;
  const int fr = lane & 15, fq = lane >> 4;

  __shared__ __align__(16) ushort Kl[64 * 72];
  __shared__ __align__(16) ushort Vt[64 * 70];
  __shared__ __align__(16) ushort Pl[4][64 * 68];

  const size_t qrow0 = (size_t)b * 4096 + (size_t)n * 256;

  bf16x8 qf[4][2];
#pragma unroll
  for (int m = 0; m < 4; m++)
#pragma unroll
    for (int kh = 0; kh < 2; kh++)
      qf[m][kh] = *(const bf16x8*)&Q[(qrow0 + wv * 64 + m * 16 + fr) * qs + h * 64 + kh * 32 + fq * 8];

  f32x4 oacc[4][4];
#pragma unroll
  for (int m = 0; m < 4; m++)
#pragma unroll
    for (int d = 0; d < 4; d++) oacc[m][d] = (f32x4)0.0f;

  float lsum[4][4];
#pragma unroll
  for (int m = 0; m < 4; m++)
#pragma unroll
    for (int j = 0; j < 4; j++) lsum[m][j] = 0.0f;

  const int c0 = (n == 0) ? 4 : 0;
  for (int c = c0; c < 8; c++) {
    const size_t kvrow0 =
        (size_t)((long long)b * 4096 + (long long)n * 256 + (long long)c * 64 - 256);
#pragma unroll
    for (int p = 0; p < 2; p++) {
      const int s = tid + p * 256;
      const int rr = s >> 3, cs2 = s & 7;
      *(u16x8*)&Kl[rr * 72 + cs2 * 8] =
          *(const u16x8*)&Kb[(kvrow0 + rr) * qs + h * 64 + cs2 * 8];
      const u16x8 vvv = *(const u16x8*)&Vb[(kvrow0 + rr) * qs + h * 64 + cs2 * 8];
#pragma unroll
      for (int i = 0; i < 8; i++) Vt[(cs2 * 8 + i) * 70 + rr] = vvv[i];
    }
    __syncthreads();

    if (c <= wv + 4) {
      const bool diag = (c == wv + 4);
#pragma unroll
      for (int nn = 0; nn < 4; nn++) {
        f32x4 sa[4];
#pragma unroll
        for (int m = 0; m < 4; m++) sa[m] = (f32x4)0.0f;
#pragma unroll
        for (int kh = 0; kh < 2; kh++) {
          const bf16x8 bk = *(const bf16x8*)&Kl[(nn * 16 + fr) * 72 + kh * 32 + fq * 8];
#pragma unroll
          for (int m = 0; m < 4; m++)
            sa[m] = MFMA_BF16(qf[m][kh], bk, sa[m], 0, 0, 0);
        }
#pragma unroll
        for (int m = 0; m < 4; m++)
#pragma unroll
          for (int j = 0; j < 4; j++) {
            float p = __expf(sa[m][j]);
            if (diag && (nn * 16 + fr > m * 16 + fq * 4 + j)) p = 0.0f;
            lsum[m][j] += p;
            Pl[wv][(m * 16 + fq * 4 + j) * 68 + nn * 16 + fr] = f2b(p);
          }
      }
      __builtin_amdgcn_s_setprio(1);
#pragma unroll
      for (int kh = 0; kh < 2; kh++) {
        bf16x8 pa[4];
#pragma unroll
        for (int m = 0; m < 4; m++)
          pa[m] = *(const bf16x8*)&Pl[wv][(m * 16 + fr) * 68 + kh * 32 + fq * 8];
#pragma unroll
        for (int d = 0; d < 4; d++) {
          const bf16x8 vb = *(const bf16x8*)&Vt[(d * 16 + fr) * 70 + kh * 32 + fq * 8];
#pragma unroll
          for (int m = 0; m < 4; m++)
            oacc[m][d] = MFMA_BF16(pa[m], vb, oacc[m][d], 0, 0, 0);
        }
      }
      __builtin_amdgcn_s_setprio(0);
    }
    __syncthreads();
  }

  float rl[4][4];
#pragma unroll
  for (int m = 0; m < 4; m++)
#pragma unroll
    for (int j = 0; j < 4; j++) {
      float t = lsum[m][j];
      t += __shfl_xor(t, 1);
      t += __shfl_xor(t, 2);
      t += __shfl_xor(t, 4);
      t += __shfl_xor(t, 8);
      rl[m][j] = 1.0f / t;
    }

#pragma unroll
  for (int m = 0; m < 4; m++)
#pragma unroll
    for (int d = 0; d < 4; d++)
#pragma unroll
      for (int j = 0; j < 4; j++) {
        const float o = oacc[m][d][j] * rl[m][j];
        O[(qrow0 + wv * 64 + m * 16 + fq * 4 + j) * 1024 + h * 64 + d * 16 + fr] = f2b(o);
      }
}

// ---------------- host launcher ----------------------------------------------
extern "C" void kernel_launch(void* const* d_in, const int* in_sizes, int n_in,
                              void* d_out, int out_size, void* d_ws, size_t ws_size,
                              hipStream_t stream) {
  (void)in_sizes; (void)n_in; (void)out_size; (void)ws_size;
  const float* x     = (const float*)d_in[0];
  const float* ln1_g = (const float*)d_in[1];
  const float* ln1_b = (const float*)d_in[2];
  const float* ln2_g = (const float*)d_in[3];
  const float* ln2_b = (const float*)d_in[4];
  const float* Wq    = (const float*)d_in[5];
  const float* Wk    = (const float*)d_in[6];
  const float* Wv    = (const float*)d_in[7];
  const float* Wo    = (const float*)d_in[8];
  const float* bo    = (const float*)d_in[9];
  const float* W1    = (const float*)d_in[10];
  const float* b1    = (const float*)d_in[11];
  const float* W2    = (const float*)d_in[12];
  const float* b2    = (const float*)d_in[13];

  char* ws = (char*)d_ws;
  const size_t MB = 1ull << 20;
  ushort* WQKVT = (ushort*)(ws + 0 * MB);   // [3072,1024]
  ushort* WOT = (ushort*)(ws + 6 * MB);     // [1024,1024]
  ushort* W1T = (ushort*)(ws + 8 * MB);     // [4096,1024]
  ushort* W2T = (ushort*)(ws + 16 * MB);    // [1024,2048]
  ushort* LN1 = (ushort*)(ws + 20 * MB);    // 32MB
  ushort* ATT = LN1;
  ushort* QKV = (ushort*)(ws + 52 * MB);    // [16384,3072] = 96MB
  ushort* LN2 = (ushort*)(ws + 52 * MB);
  ushort* U   = (ushort*)(ws + 84 * MB);    // 64MB
  float*  X1  = (float*)d_out;
  float*  OUT = (float*)d_out;

  const dim3 tb(32, 8);
  transpose_cast_kernel<<<dim3(32, 32), tb, 0, stream>>>(Wq, WQKVT, 1024, 1024);
  transpose_cast_kernel<<<dim3(32, 32), tb, 0, stream>>>(Wk, WQKVT + (size_t)1024 * 1024, 1024, 1024);
  transpose_cast_kernel<<<dim3(32, 32), tb, 0, stream>>>(Wv, WQKVT + (size_t)2048 * 1024, 1024, 1024);
  transpose_cast_kernel<<<dim3(32, 32), tb, 0, stream>>>(Wo, WOT, 1024, 1024);
  transpose_cast_kernel<<<dim3(128, 32), tb, 0, stream>>>(W1, W1T, 1024, 4096);
  transpose_cast_kernel<<<dim3(32, 64), tb, 0, stream>>>(W2, W2T, 2048, 1024);

  ln_kernel<<<16384, 256, 0, stream>>>(x, ln1_g, ln1_b, LN1);

  // fused QKV (Q pre-scaled by 1/8 in epilogue): [16384,3072]
  gemm256_kernel<2><<<64 * 12, 512, 0, stream>>>(LN1, WQKVT, 16384, 3072, 1024,
                                                 QKV, nullptr, nullptr, nullptr);

  attn_kernel<<<1024, 256, 0, stream>>>(QKV, QKV + 1024, QKV + 2048, ATT, 3072);

  // x1 = x + ATT*Wo^T + bo  (fp32, into d_out)
  gemm256_kernel<1><<<64 * 4, 512, 0, stream>>>(ATT, WOT, 16384, 1024, 1024,
                                                nullptr, X1, bo, x);

  ln_kernel<<<16384, 256, 0, stream>>>(X1, ln2_g, ln2_b, LN2);

  // U = a * gelu(g), 256x128 dual-acc 8-phase
  gemm_geglu_kernel<<<64 * 16, 512, 0, stream>>>(LN2, W1T, b1, U);

  // out = x1 + U*W2^T + b2  (in-place on d_out)
  gemm256_kernel<1><<<64 * 4, 512, 0, stream>>>(U, W2T, 16384, 1024, 2048,
                                                nullptr, OUT, b2, X1);
}

// Round 11
// 528.333 us; speedup vs baseline: 1.8560x; 1.0140x over previous
//
#include <hip/hip_runtime.h>
#include <hip/hip_bf16.h>

typedef __attribute__((ext_vector_type(4))) float f32x4;
typedef __attribute__((ext_vector_type(8))) short bf16x8;
typedef __attribute__((ext_vector_type(8))) unsigned short u16x8;

static __device__ __forceinline__ ushort f2b(float f) {
  union { float f; unsigned u; } v; v.f = f;
  unsigned r = v.u + 0x7fffu + ((v.u >> 16) & 1u);
  return (ushort)(r >> 16);
}

static __device__ __forceinline__ float gelu_fast(float g) {
  const float c0 = 0.7978845608028654f, c1 = 0.044715f;
  const float u = c0 * (g + c1 * g * g * g);
  const float e = __expf(2.0f * u);
  const float t = 1.0f - 2.0f / (e + 1.0f);
  return 0.5f * g * (1.0f + t);
}

static __device__ __forceinline__ void gload_lds16(const void* g, void* l) {
  __builtin_amdgcn_global_load_lds(
      (__attribute__((address_space(1))) void*)(g),
      (__attribute__((address_space(3))) void*)(l), 16, 0, 0);
}

#define MFMA_BF16 __builtin_amdgcn_mfma_f32_16x16x32_bf16

// ---------------- weight transpose + cast: Wt[n][k] = bf16(W[k][n]) -----------
__global__ __launch_bounds__(256) void transpose_cast_kernel(
    const float* __restrict__ W, ushort* __restrict__ Wt, int K, int N) {
  __shared__ float tile[32][33];
  const int n0 = blockIdx.x * 32, k0 = blockIdx.y * 32;
  const int tx = threadIdx.x, ty = threadIdx.y;  // 32 x 8
#pragma unroll
  for (int r = 0; r < 32; r += 8)
    tile[ty + r][tx] = W[(size_t)(k0 + ty + r) * N + n0 + tx];
  __syncthreads();
#pragma unroll
  for (int r = 0; r < 32; r += 8)
    Wt[(size_t)(n0 + ty + r) * K + k0 + tx] = f2b(tile[tx][ty + r]);
}

// ---------------- layernorm (rows of 1024 fp32) -> bf16 ----------------------
__global__ __launch_bounds__(256) void ln_kernel(
    const float* __restrict__ x, const float* __restrict__ g,
    const float* __restrict__ bb, ushort* __restrict__ out) {
  const int row = blockIdx.x;
  const float* xr = x + (size_t)row * 1024;
  const float4 v = *(const float4*)&xr[threadIdx.x * 4];
  float s = v.x + v.y + v.z + v.w;
  float s2 = v.x * v.x + v.y * v.y + v.z * v.z + v.w * v.w;
#pragma unroll
  for (int off = 32; off > 0; off >>= 1) {
    s += __shfl_down(s, off);
    s2 += __shfl_down(s2, off);
  }
  __shared__ float red[8];
  const int lane = threadIdx.x & 63, wv = threadIdx.x >> 6;
  if (lane == 0) { red[wv] = s; red[4 + wv] = s2; }
  __syncthreads();
  s = red[0] + red[1] + red[2] + red[3];
  s2 = red[4] + red[5] + red[6] + red[7];
  const float mu = s * (1.0f / 1024.0f);
  const float rs = rsqrtf(s2 * (1.0f / 1024.0f) - mu * mu + 1e-5f);
  const int c = threadIdx.x * 4;
  ushort4 o;
  o.x = f2b((v.x - mu) * rs * g[c + 0] + bb[c + 0]);
  o.y = f2b((v.y - mu) * rs * g[c + 1] + bb[c + 1]);
  o.z = f2b((v.z - mu) * rs * g[c + 2] + bb[c + 2]);
  o.w = f2b((v.w - mu) * rs * g[c + 3] + bb[c + 3]);
  *(ushort4*)&out[(size_t)row * 1024 + c] = o;
}

// ---------------- 256x256 8-phase GEMM: C = A[M,K] * Bt[N,K]^T ---------------
// 512 thr = 8 waves (2 wm x 4 wn), per-wave 128x64 out. BK=64, dbuf 128KB LDS.
// K-loop unrolled by 2 so buffer is compile-time; ds_read addrs are
// precomputed base VGPR + immediate. DSTU (staging dest) is in USHORT units:
// buffer 1 = 32768 ushorts = 65536 bytes (matches dA0 = cA0 + 65536 bytes).
template <int MODE>
__global__ __launch_bounds__(512, 2) void gemm256_kernel(
    const ushort* __restrict__ A, const ushort* __restrict__ Bt,
    const int M, const int N, const int K,
    ushort* __restrict__ Cb, float* __restrict__ Cf,
    const float* __restrict__ bias, const float* __restrict__ res) {
  __shared__ __align__(16) ushort lds[2 * 32768];  // 128KB

  const int ntn = N >> 8;
  const int bn = blockIdx.x % ntn;
  const int bm = blockIdx.x / ntn;
  const int tid = threadIdx.x;
  const int l = tid & 63, w = tid >> 6;
  const int wm = w >> 2, wn = w & 3;
  const int fr = l & 15, fq = l >> 4;

  const ushort* Ab = A + (size_t)bm * 256 * K;
  const ushort* Bb = Bt + (size_t)bn * 256 * K;

  const int lr = l >> 3;
  const int sc = (((l & 7) ^ lr) * 8);

  const char* ldsc = (const char*)lds;
  const int fr7 = fr & 7;
  const unsigned s0 = (unsigned)((fq ^ fr7) * 16);        // byte slot, kk=0
  const unsigned s1 = (unsigned)(((4 + fq) ^ fr7) * 16);  // byte slot, kk=1
  const unsigned cA0 = (unsigned)((wm * 128 + fr) * 128) + s0;
  const unsigned cA1 = (unsigned)((wm * 128 + fr) * 128) + s1;
  const unsigned cB0 = 32768u + (unsigned)((wn * 64 + fr) * 128) + s0;
  const unsigned cB1 = 32768u + (unsigned)((wn * 64 + fr) * 128) + s1;
  const unsigned dA0 = cA0 + 65536u, dA1 = cA1 + 65536u;
  const unsigned dB0 = cB0 + 65536u, dB1 = cB1 + 65536u;

  f32x4 acc[8][4];
#pragma unroll
  for (int m = 0; m < 8; m++)
#pragma unroll
    for (int n = 0; n < 4; n++) acc[m][n] = (f32x4)0.0f;

  const int NT = K >> 6;

#define STG_A(h, tt, DSTU)                                                     \
  { _Pragma("unroll") for (int i = 0; i < 2; i++) {                            \
      const int rr = (h) * 128 + i * 64 + w * 8;                               \
      gload_lds16(Ab + (size_t)(rr + lr) * K + (size_t)(tt) * 64 + sc,         \
                  &lds[(DSTU) + rr * 64]); } }
#define STG_B(h, tt, DSTU)                                                     \
  { _Pragma("unroll") for (int i = 0; i < 2; i++) {                            \
      const int rr = (h) * 128 + i * 64 + w * 8;                               \
      gload_lds16(Bb + (size_t)(rr + lr) * K + (size_t)(tt) * 64 + sc,         \
                  &lds[(DSTU) + 16384 + rr * 64]); } }

#define GPHASES(tt, bA0v, bA1v, bB0v, bB1v, DSTU, HASNEXT)                     \
  {                                                                            \
    bf16x8 af[4][2], bfv[4][2];                                                \
    /* phase 0: publish tile; MFMA m0-3 x n0-1 */                              \
    if (HASNEXT) {                                                             \
      STG_A(0, (tt) + 1, DSTU);                                                \
      asm volatile("s_waitcnt vmcnt(2)" ::: "memory");                         \
    } else {                                                                   \
      asm volatile("s_waitcnt vmcnt(0)" ::: "memory");                         \
    }                                                                          \
    __builtin_amdgcn_s_barrier();                                              \
    asm volatile("" ::: "memory");                                             \
    _Pragma("unroll") for (int m = 0; m < 4; m++) {                            \
      af[m][0] = *(const bf16x8*)(ldsc + (bA0v) + m * 2048);                   \
      af[m][1] = *(const bf16x8*)(ldsc + (bA1v) + m * 2048);                   \
    }                                                                          \
    _Pragma("unroll") for (int n = 0; n < 2; n++) {                            \
      bfv[n][0] = *(const bf16x8*)(ldsc + (bB0v) + n * 2048);                  \
      bfv[n][1] = *(const bf16x8*)(ldsc + (bB1v) + n * 2048);                  \
    }                                                                          \
    __builtin_amdgcn_s_setprio(1);                                             \
    _Pragma("unroll") for (int m = 0; m < 4; m++)                              \
      _Pragma("unroll") for (int n = 0; n < 2; n++)                            \
        _Pragma("unroll") for (int kk = 0; kk < 2; kk++)                       \
          acc[m][n] = MFMA_BF16(af[m][kk], bfv[n][kk], acc[m][n], 0, 0, 0);    \
    __builtin_amdgcn_s_setprio(0);                                             \
    asm volatile("" ::: "memory");                                             \
    __builtin_amdgcn_s_barrier();                                              \
    /* phase 1: MFMA m0-3 x n2-3 */                                            \
    if (HASNEXT) STG_A(1, (tt) + 1, DSTU);                                     \
    _Pragma("unroll") for (int n = 2; n < 4; n++) {                            \
      bfv[n][0] = *(const bf16x8*)(ldsc + (bB0v) + n * 2048);                  \
      bfv[n][1] = *(const bf16x8*)(ldsc + (bB1v) + n * 2048);                  \
    }                                                                          \
    __builtin_amdgcn_s_barrier();                                              \
    asm volatile("" ::: "memory");                                             \
    __builtin_amdgcn_s_setprio(1);                                             \
    _Pragma("unroll") for (int m = 0; m < 4; m++)                              \
      _Pragma("unroll") for (int n = 2; n < 4; n++)                            \
        _Pragma("unroll") for (int kk = 0; kk < 2; kk++)                       \
          acc[m][n] = MFMA_BF16(af[m][kk], bfv[n][kk], acc[m][n], 0, 0, 0);    \
    __builtin_amdgcn_s_setprio(0);                                             \
    asm volatile("" ::: "memory");                                             \
    __builtin_amdgcn_s_barrier();                                              \
    /* phase 2: MFMA m4-7 x n0-1 */                                            \
    if (HASNEXT) STG_B(0, (tt) + 1, DSTU);                                     \
    _Pragma("unroll") for (int m = 0; m < 4; m++) {                            \
      af[m][0] = *(const bf16x8*)(ldsc + (bA0v) + (m + 4) * 2048);             \
      af[m][1] = *(const bf16x8*)(ldsc + (bA1v) + (m + 4) * 2048);             \
    }                                                                          \
    __builtin_amdgcn_s_barrier();                                              \
    asm volatile("" ::: "memory");                                             \
    __builtin_amdgcn_s_setprio(1);                                             \
    _Pragma("unroll") for (int m = 0; m < 4; m++)                              \
      _Pragma("unroll") for (int n = 0; n < 2; n++)                            \
        _Pragma("unroll") for (int kk = 0; kk < 2; kk++)                       \
          acc[m + 4][n] = MFMA_BF16(af[m][kk], bfv[n][kk], acc[m + 4][n], 0, 0, 0); \
    __builtin_amdgcn_s_setprio(0);                                             \
    asm volatile("" ::: "memory");                                             \
    __builtin_amdgcn_s_barrier();                                              \
    /* phase 3: MFMA m4-7 x n2-3 */                                            \
    if (HASNEXT) STG_B(1, (tt) + 1, DSTU);                                     \
    __builtin_amdgcn_s_barrier();                                              \
    asm volatile("" ::: "memory");                                             \
    __builtin_amdgcn_s_setprio(1);                                             \
    _Pragma("unroll") for (int m = 0; m < 4; m++)                              \
      _Pragma("unroll") for (int n = 2; n < 4; n++)                            \
        _Pragma("unroll") for (int kk = 0; kk < 2; kk++)                       \
          acc[m + 4][n] = MFMA_BF16(af[m][kk], bfv[n][kk], acc[m + 4][n], 0, 0, 0); \
    __builtin_amdgcn_s_setprio(0);                                             \
    asm volatile("" ::: "memory");                                             \
    __builtin_amdgcn_s_barrier();                                              \
  }

  STG_A(0, 0, 0); STG_A(1, 0, 0); STG_B(0, 0, 0); STG_B(1, 0, 0);

  for (int t = 0; t < NT; t += 2) {
    GPHASES(t, cA0, cA1, cB0, cB1, 32768, true);
    GPHASES(t + 1, dA0, dA1, dB0, dB1, 0, (t + 2 < NT));
  }
#undef GPHASES
#undef STG_A
#undef STG_B

  const int rowb = bm * 256 + wm * 128 + fq * 4;
  const int colb = bn * 256 + wn * 64 + fr;
#pragma unroll
  for (int m = 0; m < 8; m++) {
#pragma unroll
    for (int n = 0; n < 4; n++) {
      const int col = colb + n * 16;
#pragma unroll
      for (int j = 0; j < 4; j++) {
        const int row = rowb + m * 16 + j;
        float vv = acc[m][n][j];
        if (MODE == 0) {
          Cb[(size_t)row * N + col] = f2b(vv);
        } else if (MODE == 2) {
          if (col < 1024) vv *= 0.125f;
          Cb[(size_t)row * N + col] = f2b(vv);
        } else {
          Cf[(size_t)row * N + col] = vv + bias[col] + res[(size_t)row * N + col];
        }
      }
    }
  }
}

// ---------------- GEGLU GEMM, 8-phase, immediate-offset addressing -----------
// 256 rows x 128 U-cols; dual acc (a,g). LDS/buf: A 32KB + Ba 16KB + Bg 16KB,
// x2 = 128KB. DSTU in USHORT units: buffer 1 = 32768.
__global__ __launch_bounds__(512, 2) void gemm_geglu_kernel(
    const ushort* __restrict__ A, const ushort* __restrict__ W1t,
    const float* __restrict__ b1, ushort* __restrict__ U) {
  const int K = 1024;
  __shared__ __align__(16) ushort lds[2 * 32768];  // 128 KB

  const int bn = blockIdx.x & 15;
  const int bm = blockIdx.x >> 4;
  const int tid = threadIdx.x;
  const int l = tid & 63, w = tid >> 6;
  const int wm = w >> 2, wn = w & 3;
  const int fr = l & 15, fq = l >> 4;

  const ushort* Ab = A + (size_t)bm * 256 * K;
  const ushort* Bab = W1t + (size_t)bn * 128 * K;
  const ushort* Bgb = W1t + (size_t)(2048 + bn * 128) * K;

  const int lr = l >> 3;
  const int sc = (((l & 7) ^ lr) * 8);

  const char* ldsc = (const char*)lds;
  const int fr7 = fr & 7;
  const unsigned s0 = (unsigned)((fq ^ fr7) * 16);
  const unsigned s1 = (unsigned)(((4 + fq) ^ fr7) * 16);
  const unsigned cA0 = (unsigned)((wm * 128 + fr) * 128) + s0;
  const unsigned cA1 = (unsigned)((wm * 128 + fr) * 128) + s1;
  const unsigned cBa0 = 32768u + (unsigned)((wn * 32 + fr) * 128) + s0;
  const unsigned cBa1 = 32768u + (unsigned)((wn * 32 + fr) * 128) + s1;
  const unsigned dA0 = cA0 + 65536u, dA1 = cA1 + 65536u;
  const unsigned dBa0 = cBa0 + 65536u, dBa1 = cBa1 + 65536u;

  f32x4 acca[8][2], accg[8][2];
#pragma unroll
  for (int m = 0; m < 8; m++)
#pragma unroll
    for (int n = 0; n < 2; n++) { acca[m][n] = (f32x4)0.0f; accg[m][n] = (f32x4)0.0f; }

  const int NT = K >> 6;  // 16

#define STG_GA(h, tt, DSTU)                                                    \
  { _Pragma("unroll") for (int i = 0; i < 2; i++) {                            \
      const int rr = (h) * 128 + i * 64 + w * 8;                               \
      gload_lds16(Ab + (size_t)(rr + lr) * K + (size_t)(tt) * 64 + sc,         \
                  &lds[(DSTU) + rr * 64]); } }
#define STG_BA(tt, DSTU)                                                       \
  { _Pragma("unroll") for (int i = 0; i < 2; i++) {                            \
      const int rr = i * 64 + w * 8;                                           \
      gload_lds16(Bab + (size_t)(rr + lr) * K + (size_t)(tt) * 64 + sc,        \
                  &lds[(DSTU) + 16384 + rr * 64]); } }
#define STG_BG(tt, DSTU)                                                       \
  { _Pragma("unroll") for (int i = 0; i < 2; i++) {                            \
      const int rr = i * 64 + w * 8;                                           \
      gload_lds16(Bgb + (size_t)(rr + lr) * K + (size_t)(tt) * 64 + sc,        \
                  &lds[(DSTU) + 24576 + rr * 64]); } }

#define GLPHASES(tt, bA0v, bA1v, bBa0v, bBa1v, DSTU, HASNEXT)                  \
  {                                                                            \
    bf16x8 af[4][2], ba[2][2], bg[2][2];                                       \
    /* phase 0: publish; a-MFMA m0-3 */                                        \
    if (HASNEXT) {                                                             \
      STG_GA(0, (tt) + 1, DSTU);                                               \
      asm volatile("s_waitcnt vmcnt(2)" ::: "memory");                         \
    } else {                                                                   \
      asm volatile("s_waitcnt vmcnt(0)" ::: "memory");                         \
    }                                                                          \
    __builtin_amdgcn_s_barrier();                                              \
    asm volatile("" ::: "memory");                                             \
    _Pragma("unroll") for (int m = 0; m < 4; m++) {                            \
      af[m][0] = *(const bf16x8*)(ldsc + (bA0v) + m * 2048);                   \
      af[m][1] = *(const bf16x8*)(ldsc + (bA1v) + m * 2048);                   \
    }                                                                          \
    _Pragma("unroll") for (int n = 0; n < 2; n++) {                            \
      ba[n][0] = *(const bf16x8*)(ldsc + (bBa0v) + n * 2048);                  \
      ba[n][1] = *(const bf16x8*)(ldsc + (bBa1v) + n * 2048);                  \
    }                                                                          \
    __builtin_amdgcn_s_setprio(1);                                             \
    _Pragma("unroll") for (int m = 0; m < 4; m++)                              \
      _Pragma("unroll") for (int n = 0; n < 2; n++)                            \
        _Pragma("unroll") for (int kk = 0; kk < 2; kk++)                       \
          acca[m][n] = MFMA_BF16(af[m][kk], ba[n][kk], acca[m][n], 0, 0, 0);   \
    __builtin_amdgcn_s_setprio(0);                                             \
    asm volatile("" ::: "memory");                                             \
    __builtin_amdgcn_s_barrier();                                              \
    /* phase 1: g-MFMA m0-3 */                                                 \
    if (HASNEXT) STG_GA(1, (tt) + 1, DSTU);                                    \
    _Pragma("unroll") for (int n = 0; n < 2; n++) {                            \
      bg[n][0] = *(const bf16x8*)(ldsc + (bBa0v) + 16384 + n * 2048);          \
      bg[n][1] = *(const bf16x8*)(ldsc + (bBa1v) + 16384 + n * 2048);          \
    }                                                                          \
    __builtin_amdgcn_s_barrier();                                              \
    asm volatile("" ::: "memory");                                             \
    __builtin_amdgcn_s_setprio(1);                                             \
    _Pragma("unroll") for (int m = 0; m < 4; m++)                              \
      _Pragma("unroll") for (int n = 0; n < 2; n++)                            \
        _Pragma("unroll") for (int kk = 0; kk < 2; kk++)                       \
          accg[m][n] = MFMA_BF16(af[m][kk], bg[n][kk], accg[m][n], 0, 0, 0);   \
    __builtin_amdgcn_s_setprio(0);                                             \
    asm volatile("" ::: "memory");                                             \
    __builtin_amdgcn_s_barrier();                                              \
    /* phase 2: a-MFMA m4-7 */                                                 \
    if (HASNEXT) STG_BA((tt) + 1, DSTU);                                       \
    _Pragma("unroll") for (int m = 0; m < 4; m++) {                            \
      af[m][0] = *(const bf16x8*)(ldsc + (bA0v) + (m + 4) * 2048);             \
      af[m][1] = *(const bf16x8*)(ldsc + (bA1v) + (m + 4) * 2048);             \
    }                                                                          \
    __builtin_amdgcn_s_barrier();                                              \
    asm volatile("" ::: "memory");                                             \
    __builtin_amdgcn_s_setprio(1);                                             \
    _Pragma("unroll") for (int m = 0; m < 4; m++)                              \
      _Pragma("unroll") for (int n = 0; n < 2; n++)                            \
        _Pragma("unroll") for (int kk = 0; kk < 2; kk++)                       \
          acca[m + 4][n] = MFMA_BF16(af[m][kk], ba[n][kk], acca[m + 4][n], 0, 0, 0); \
    __builtin_amdgcn_s_setprio(0);                                             \
    asm volatile("" ::: "memory");                                             \
    __builtin_amdgcn_s_barrier();                                              \
    /* phase 3: g-MFMA m4-7 */                                                 \
    if (HASNEXT) STG_BG((tt) + 1, DSTU);                                       \
    __builtin_amdgcn_s_barrier();                                              \
    asm volatile("" ::: "memory");                                             \
    __builtin_amdgcn_s_setprio(1);                                             \
    _Pragma("unroll") for (int m = 0; m < 4; m++)                              \
      _Pragma("unroll") for (int n = 0; n < 2; n++)                            \
        _Pragma("unroll") for (int kk = 0; kk < 2; kk++)                       \
          accg[m + 4][n] = MFMA_BF16(af[m][kk], bg[n][kk], accg[m + 4][n], 0, 0, 0); \
    __builtin_amdgcn_s_setprio(0);                                             \
    asm volatile("" ::: "memory");                                             \
    __builtin_amdgcn_s_barrier();                                              \
  }

  STG_GA(0, 0, 0); STG_GA(1, 0, 0); STG_BA(0, 0); STG_BG(0, 0);

  for (int t = 0; t < NT; t += 2) {
    GLPHASES(t, cA0, cA1, cBa0, cBa1, 32768, true);
    GLPHASES(t + 1, dA0, dA1, dBa0, dBa1, 0, (t + 2 < NT));
  }
#undef GLPHASES
#undef STG_GA
#undef STG_BA
#undef STG_BG

  const int rowb = bm * 256 + wm * 128 + fq * 4;
  const int colb = bn * 128 + wn * 32 + fr;
#pragma unroll
  for (int m = 0; m < 8; m++) {
#pragma unroll
    for (int n = 0; n < 2; n++) {
      const int col = colb + n * 16;
      const float b1a = b1[col];
      const float b1g = b1[2048 + col];
#pragma unroll
      for (int j = 0; j < 4; j++) {
        const int row = rowb + m * 16 + j;
        const float a = acca[m][n][j] + b1a;
        const float gg = accg[m][n][j] + b1g;
        U[(size_t)row * 2048 + col] = f2b(a * gelu_fast(gg));
      }
    }
  }
}

// ---------------- windowed causal attention (no-max online softmax) ----------
__global__ __launch_bounds__(256, 3) void attn_kernel(
    const ushort* __restrict__ Q, const ushort* __restrict__ Kb,
    const ushort* __restrict__ Vb, ushort* __restrict__ O, const int qs) {
  const int bx = blockIdx.x;
  const int n = bx & 15;
  const int h = (bx >> 4) & 15;
  const int b = bx >> 8;
  const int tid = threadIdx.x;
  const int lane = tid & 63, wv = tid >> 6;
  const int fr = lane & 15, fq = lane >> 4;

  __shared__ __align__(16) ushort Kl[64 * 72];
  __shared__ __align__(16) ushort Vt[64 * 70];
  __shared__ __align__(16) ushort Pl[4][64 * 68];

  const size_t qrow0 = (size_t)b * 4096 + (size_t)n * 256;

  bf16x8 qf[4][2];
#pragma unroll
  for (int m = 0; m < 4; m++)
#pragma unroll
    for (int kh = 0; kh < 2; kh++)
      qf[m][kh] = *(const bf16x8*)&Q[(qrow0 + wv * 64 + m * 16 + fr) * qs + h * 64 + kh * 32 + fq * 8];

  f32x4 oacc[4][4];
#pragma unroll
  for (int m = 0; m < 4; m++)
#pragma unroll
    for (int d = 0; d < 4; d++) oacc[m][d] = (f32x4)0.0f;

  float lsum[4][4];
#pragma unroll
  for (int m = 0; m < 4; m++)
#pragma unroll
    for (int j = 0; j < 4; j++) lsum[m][j] = 0.0f;

  const int c0 = (n == 0) ? 4 : 0;
  for (int c = c0; c < 8; c++) {
    const size_t kvrow0 =
        (size_t)((long long)b * 4096 + (long long)n * 256 + (long long)c * 64 - 256);
#pragma unroll
    for (int p = 0; p < 2; p++) {
      const int s = tid + p * 256;
      const int rr = s >> 3, cs2 = s & 7;
      *(u16x8*)&Kl[rr * 72 + cs2 * 8] =
          *(const u16x8*)&Kb[(kvrow0 + rr) * qs + h * 64 + cs2 * 8];
      const u16x8 vvv = *(const u16x8*)&Vb[(kvrow0 + rr) * qs + h * 64 + cs2 * 8];
#pragma unroll
      for (int i = 0; i < 8; i++) Vt[(cs2 * 8 + i) * 70 + rr] = vvv[i];
    }
    __syncthreads();

    if (c <= wv + 4) {
      const bool diag = (c == wv + 4);
#pragma unroll
      for (int nn = 0; nn < 4; nn++) {
        f32x4 sa[4];
#pragma unroll
        for (int m = 0; m < 4; m++) sa[m] = (f32x4)0.0f;
#pragma unroll
        for (int kh = 0; kh < 2; kh++) {
          const bf16x8 bk = *(const bf16x8*)&Kl[(nn * 16 + fr) * 72 + kh * 32 + fq * 8];
#pragma unroll
          for (int m = 0; m < 4; m++)
            sa[m] = MFMA_BF16(qf[m][kh], bk, sa[m], 0, 0, 0);
        }
#pragma unroll
        for (int m = 0; m < 4; m++)
#pragma unroll
          for (int j = 0; j < 4; j++) {
            float p = __expf(sa[m][j]);
            if (diag && (nn * 16 + fr > m * 16 + fq * 4 + j)) p = 0.0f;
            lsum[m][j] += p;
            Pl[wv][(m * 16 + fq * 4 + j) * 68 + nn * 16 + fr] = f2b(p);
          }
      }
      __builtin_amdgcn_s_setprio(1);
#pragma unroll
      for (int kh = 0; kh < 2; kh++) {
        bf16x8 pa[4];
#pragma unroll
        for (int m = 0; m < 4; m++)
          pa[m] = *(const bf16x8*)&Pl[wv][(m * 16 + fr) * 68 + kh * 32 + fq * 8];
#pragma unroll
        for (int d = 0; d < 4; d++) {
          const bf16x8 vb = *(const bf16x8*)&Vt[(d * 16 + fr) * 70 + kh * 32 + fq * 8];
#pragma unroll
          for (int m = 0; m < 4; m++)
            oacc[m][d] = MFMA_BF16(pa[m], vb, oacc[m][d], 0, 0, 0);
        }
      }
      __builtin_amdgcn_s_setprio(0);
    }
    __syncthreads();
  }

  float rl[4][4];
#pragma unroll
  for (int m = 0; m < 4; m++)
#pragma unroll
    for (int j = 0; j < 4; j++) {
      float t = lsum[m][j];
      t += __shfl_xor(t, 1);
      t += __shfl_xor(t, 2);
      t += __shfl_xor(t, 4);
      t += __shfl_xor(t, 8);
      rl[m][j] = 1.0f / t;
    }

#pragma unroll
  for (int m = 0; m < 4; m++)
#pragma unroll
    for (int d = 0; d < 4; d++)
#pragma unroll
      for (int j = 0; j < 4; j++) {
        const float o = oacc[m][d][j] * rl[m][j];
        O[(qrow0 + wv * 64 + m * 16 + fq * 4 + j) * 1024 + h * 64 + d * 16 + fr] = f2b(o);
      }
}

// ---------------- host launcher ----------------------------------------------
extern "C" void kernel_launch(void* const* d_in, const int* in_sizes, int n_in,
                              void* d_out, int out_size, void* d_ws, size_t ws_size,
                              hipStream_t stream) {
  (void)in_sizes; (void)n_in; (void)out_size; (void)ws_size;
  const float* x     = (const float*)d_in[0];
  const float* ln1_g = (const float*)d_in[1];
  const float* ln1_b = (const float*)d_in[2];
  const float* ln2_g = (const float*)d_in[3];
  const float* ln2_b = (const float*)d_in[4];
  const float* Wq    = (const float*)d_in[5];
  const float* Wk    = (const float*)d_in[6];
  const float* Wv    = (const float*)d_in[7];
  const float* Wo    = (const float*)d_in[8];
  const float* bo    = (const float*)d_in[9];
  const float* W1    = (const float*)d_in[10];
  const float* b1    = (const float*)d_in[11];
  const float* W2    = (const float*)d_in[12];
  const float* b2    = (const float*)d_in[13];

  char* ws = (char*)d_ws;
  const size_t MB = 1ull << 20;
  ushort* WQKVT = (ushort*)(ws + 0 * MB);   // [3072,1024]
  ushort* WOT = (ushort*)(ws + 6 * MB);     // [1024,1024]
  ushort* W1T = (ushort*)(ws + 8 * MB);     // [4096,1024]
  ushort* W2T = (ushort*)(ws + 16 * MB);    // [1024,2048]
  ushort* LN1 = (ushort*)(ws + 20 * MB);    // 32MB
  ushort* ATT = LN1;
  ushort* QKV = (ushort*)(ws + 52 * MB);    // [16384,3072] = 96MB
  ushort* LN2 = (ushort*)(ws + 52 * MB);
  ushort* U   = (ushort*)(ws + 84 * MB);    // 64MB
  float*  X1  = (float*)d_out;
  float*  OUT = (float*)d_out;

  const dim3 tb(32, 8);
  transpose_cast_kernel<<<dim3(32, 32), tb, 0, stream>>>(Wq, WQKVT, 1024, 1024);
  transpose_cast_kernel<<<dim3(32, 32), tb, 0, stream>>>(Wk, WQKVT + (size_t)1024 * 1024, 1024, 1024);
  transpose_cast_kernel<<<dim3(32, 32), tb, 0, stream>>>(Wv, WQKVT + (size_t)2048 * 1024, 1024, 1024);
  transpose_cast_kernel<<<dim3(32, 32), tb, 0, stream>>>(Wo, WOT, 1024, 1024);
  transpose_cast_kernel<<<dim3(128, 32), tb, 0, stream>>>(W1, W1T, 1024, 4096);
  transpose_cast_kernel<<<dim3(32, 64), tb, 0, stream>>>(W2, W2T, 2048, 1024);

  ln_kernel<<<16384, 256, 0, stream>>>(x, ln1_g, ln1_b, LN1);

  // fused QKV (Q pre-scaled by 1/8 in epilogue): [16384,3072]
  gemm256_kernel<2><<<64 * 12, 512, 0, stream>>>(LN1, WQKVT, 16384, 3072, 1024,
                                                 QKV, nullptr, nullptr, nullptr);

  attn_kernel<<<1024, 256, 0, stream>>>(QKV, QKV + 1024, QKV + 2048, ATT, 3072);

  // x1 = x + ATT*Wo^T + bo  (fp32, into d_out)
  gemm256_kernel<1><<<64 * 4, 512, 0, stream>>>(ATT, WOT, 16384, 1024, 1024,
                                                nullptr, X1, bo, x);

  ln_kernel<<<16384, 256, 0, stream>>>(X1, ln2_g, ln2_b, LN2);

  // U = a * gelu(g), 256x128 dual-acc 8-phase
  gemm_geglu_kernel<<<64 * 16, 512, 0, stream>>>(LN2, W1T, b1, U);

  // out = x1 + U*W2^T + b2  (in-place on d_out)
  gemm256_kernel<1><<<64 * 4, 512, 0, stream>>>(U, W2T, 16384, 1024, 2048,
                                                nullptr, OUT, b2, X1);
}